// Round 4
// baseline (834.544 us; speedup 1.0000x reference)
//
#include <hip/hip_runtime.h>

typedef __attribute__((ext_vector_type(4))) float f32x4;
typedef __attribute__((ext_vector_type(8))) short short8;
typedef __attribute__((ext_vector_type(8))) unsigned short ushort8;
typedef unsigned short u16;
typedef unsigned int u32;

#define DMODEL 1024
#define DINNER 2048
#define NH     32
#define DIP    4288
#define DIP_PAD 4352
#define CONVD  2176
#define LSEQ   2048
#define ROWS   8192
#define NCHUNK 32

static __device__ __forceinline__ float bf2f(u16 u) {
  u32 x = ((u32)u) << 16;
  return __builtin_bit_cast(float, x);
}
static __device__ __forceinline__ u16 f2bf(float f) {
  u32 x = __builtin_bit_cast(u32, f);
  x += 0x7fffu + ((x >> 16) & 1u);
  return (u16)(x >> 16);
}
static __device__ __forceinline__ f32x4 mfma16(short8 a, short8 b, f32x4 c) {
  return __builtin_amdgcn_mfma_f32_16x16x32_bf16(a, b, c, 0, 0, 0);
}

#define GLDS(gp, lp)                                                     \
  __builtin_amdgcn_global_load_lds(                                     \
      (const __attribute__((address_space(1))) void*)(gp),              \
      (__attribute__((address_space(3))) void*)(lp), 16, 0, 0)

// ---------------- f32 -> bf16 weight cast ----------------
__global__ __launch_bounds__(256) void k_cast(const float* __restrict__ s, u16* __restrict__ d) {
  size_t i = ((size_t)blockIdx.x * 256 + threadIdx.x) * 4;
  float4 v = *(const float4*)(s + i);
  u32 lo = (u32)f2bf(v.x) | ((u32)f2bf(v.y) << 16);
  u32 hi = (u32)f2bf(v.z) | ((u32)f2bf(v.w) << 16);
  *(uint2*)(d + i) = make_uint2(lo, hi);
}

// ---------------- res = h + r ; hnorm = rmsnorm(res)*w (bf16) ----------------
__global__ __launch_bounds__(256) void k_addnorm(const float* __restrict__ h,
                                                 const float* __restrict__ r,
                                                 const float* __restrict__ nw,
                                                 float* __restrict__ res,
                                                 u16* __restrict__ hn) {
  int row = blockIdx.x, t = threadIdx.x;
  const float4* hp = (const float4*)(h + (size_t)row * DMODEL);
  const float4* rp = (const float4*)(r + (size_t)row * DMODEL);
  float4 a = hp[t], b = rp[t];
  float4 s;
  s.x = a.x + b.x; s.y = a.y + b.y; s.z = a.z + b.z; s.w = a.w + b.w;
  ((float4*)(res + (size_t)row * DMODEL))[t] = s;
  float ss = s.x * s.x + s.y * s.y + s.z * s.z + s.w * s.w;
  for (int m = 32; m; m >>= 1) ss += __shfl_xor(ss, m);
  __shared__ float wsum[4];
  if ((t & 63) == 0) wsum[t >> 6] = ss;
  __syncthreads();
  float tot = wsum[0] + wsum[1] + wsum[2] + wsum[3];
  float rinv = rsqrtf(tot * (1.0f / DMODEL) + 1e-5f);
  float4 w4 = ((const float4*)nw)[t];
  u32 lo = (u32)f2bf(s.x * rinv * w4.x) | ((u32)f2bf(s.y * rinv * w4.y) << 16);
  u32 hi = (u32)f2bf(s.z * rinv * w4.z) | ((u32)f2bf(s.w * rinv * w4.w) << 16);
  *(uint2*)(hn + (size_t)row * DMODEL + t * 4) = make_uint2(lo, hi);
}

// ---------------- LDS-staged bf16 MFMA GEMM, counted-vmcnt depth-2 pipeline ----------------
// 128x128 tile, BK=32, 4 waves (2x2), each wave 64x64 via 4x4 mfma_16x16x32.
// Raw s_barrier + s_waitcnt vmcnt(4): tile t+1's loads stay in flight across the
// barrier; each tile's loads land ~2 compute-phases after issue (T3/T4 recipe).
template <int MODE>
__global__ __launch_bounds__(256) void k_gemm(const u16* __restrict__ A,
                                              const u16* __restrict__ Bw, int K,
                                              float* __restrict__ outf,
                                              u16* __restrict__ zb, u16* __restrict__ xb,
                                              float* __restrict__ dtp,
                                              const float* __restrict__ dt_bias) {
  __shared__ u16 sA[2][128 * 32];
  __shared__ u16 sB[2][128 * 32];
  const int tid = threadIdx.x, wave = tid >> 6;
  const int lane = tid & 63;
  const int wm = wave >> 1, wn = wave & 1;
  const int lr = lane & 15, lg = lane >> 4;
  const int brow = blockIdx.x * 128, bcol = blockIdx.y * 128;
  const int srow = tid >> 2, scol = (tid & 3) * 8;
  const u16* gA = A + (size_t)(brow + srow) * K + scol;
  const u16* gB = Bw + (size_t)(bcol + srow) * K + scol;
  const size_t rstep = (size_t)64 * K;
  const int nk = K >> 5;

  f32x4 acc[4][4] = {};

  auto STAGE = [&](int buf, int k0) {
    char* lA = (char*)(&sA[buf][0]) + wave * 1024;
    char* lB = (char*)(&sB[buf][0]) + wave * 1024;
    GLDS(gA + k0, lA);
    GLDS(gA + rstep + k0, lA + 4096);
    GLDS(gB + k0, lB);
    GLDS(gB + rstep + k0, lB + 4096);
  };

  STAGE(0, 0);
  STAGE(1, 32);
  for (int t = 0; t < nk; ++t) {
    const int cur = t & 1;
    if (t + 1 < nk)
      asm volatile("s_waitcnt vmcnt(4)" ::: "memory");
    else
      asm volatile("s_waitcnt vmcnt(0)" ::: "memory");
    __builtin_amdgcn_s_barrier();
    __builtin_amdgcn_sched_barrier(0);
    short8 af[4], bf[4];
#pragma unroll
    for (int i = 0; i < 4; ++i) {
      af[i] = *(const short8*)&sA[cur][(wm * 64 + i * 16 + lr) * 32 + lg * 8];
      bf[i] = *(const short8*)&sB[cur][(wn * 64 + i * 16 + lr) * 32 + lg * 8];
    }
#pragma unroll
    for (int i = 0; i < 4; ++i)
#pragma unroll
      for (int j = 0; j < 4; ++j) acc[i][j] = mfma16(af[i], bf[j], acc[i][j]);
    __builtin_amdgcn_sched_barrier(0);
    __builtin_amdgcn_s_barrier();
    __builtin_amdgcn_sched_barrier(0);
    if (t + 2 < nk) STAGE(cur, (t + 2) << 5);
  }

  const int mb = brow + wm * 64 + lg * 4;
  const int nb = bcol + wn * 64 + lr;
#pragma unroll
  for (int i = 0; i < 4; ++i)
#pragma unroll
    for (int j = 0; j < 4; ++j)
#pragma unroll
      for (int rr = 0; rr < 4; ++rr) {
        int m = mb + i * 16 + rr;
        int n = nb + j * 16;
        float v = acc[i][j][rr];
        if constexpr (MODE == 1) {
          outf[(size_t)m * 1024 + n] = v;
        } else {
          if (n < DINNER) {
            zb[(size_t)m * DINNER + n] = f2bf(v);
          } else if (n < DINNER + CONVD) {
            xb[(size_t)m * CONVD + (n - DINNER)] = f2bf(v);
          } else if (n < DIP) {
            int h2 = n - (DINNER + CONVD);  // 0..63
            float uu = v + dt_bias[h2 & 31];
            float sp = (uu > 20.f) ? uu : log1pf(expf(uu));
            int bb = m >> 11, tt = m & 2047;
            int obb = bb, ot = tt;
            if (h2 >= 32) { obb = bb + 4; ot = 2047 - tt; }
            dtp[((size_t)(obb << 11) + ot) * NH + (h2 & 31)] = sp;
          }
        }
      }
}

// ---------------- depthwise causal conv (k=4) + SiLU, 8 chans/thread ----------------
__global__ __launch_bounds__(256) void k_conv(const u16* __restrict__ xbc,
                                              const float* __restrict__ cw,
                                              const float* __restrict__ cb,
                                              u16* __restrict__ xc, u16* __restrict__ bm,
                                              u16* __restrict__ cm) {
  int e = blockIdx.x * 256 + threadIdx.x;  // e < ROWS*272
  int c8 = e % 272;
  int r = e / 272;
  int c = c8 * 8;
  int b = r >> 11, t = r & 2047;
  float4 w[8];
  float a[8];
#pragma unroll
  for (int j = 0; j < 8; ++j) {
    w[j] = *(const float4*)&cw[(c + j) * 4];
    a[j] = cb[c + j];
  }
  const u16* base = xbc + (size_t)(b << 11) * CONVD + c;
#pragma unroll
  for (int k = 0; k < 4; ++k) {
    int tt = t - 3 + k;
    if (tt >= 0) {
      ushort8 v = *(const ushort8*)(base + (size_t)tt * CONVD);
#pragma unroll
      for (int j = 0; j < 8; ++j) a[j] += bf2f(v[j]) * ((const float*)&w[j])[k];
    }
  }
  ushort8 o;
#pragma unroll
  for (int j = 0; j < 8; ++j) {
    float s = a[j] * (1.f / (1.f + expf(-a[j])));
    o[j] = f2bf(s);
  }
  if (c8 < 256) *(ushort8*)(xc + (size_t)r * DINNER + c) = o;
  else if (c8 < 264) *(ushort8*)(bm + (size_t)r * 64 + (c - DINNER)) = o;
  else *(ushort8*)(cm + (size_t)r * 64 + (c - DINNER - 64)) = o;
}

// ---------------- fused SSD scan: one block per (dir, batch, head) ----------------
__global__ __launch_bounds__(256) void k_ssd(const u16* __restrict__ xc,
                                             const u16* __restrict__ bmat,
                                             const u16* __restrict__ cmat,
                                             const float* __restrict__ dtp,
                                             const float* __restrict__ alog,
                                             u16* __restrict__ y0, u16* __restrict__ y1) {
  const int h = blockIdx.x & 31;
  const int grp = blockIdx.x >> 5;  // 0..7
  const int dir = grp >> 2;
  const int bt = grp & 3;
  const int tid = threadIdx.x, wave = tid >> 6, lane = tid & 63;
  const float Ah = -expf(alog[h]);

  __shared__ u16 sB[64][72];   // [s][n]
  __shared__ u16 sC[64][72];   // [s][n]
  __shared__ u16 sXM[64][72];  // staged X [s][p]; after transpose reused as M [l][s]
  __shared__ u16 sXT[64][72];  // X^T [p][s]
  __shared__ u16 sBT[64][72];  // B^T [n][s]
  __shared__ float sS[64][68]; // [p][n] running inter-chunk state (f32)
  __shared__ float sAc[64], sEA[64], sSc[64], sDt[64];

  for (int i = tid; i < 64 * 64; i += 256) sS[i >> 6][i & 63] = 0.f;

  const int lr = lane & 15, lg = lane >> 4;
  const int srow = tid >> 2, q = tid & 3;
  const int tp = tid >> 2, ts0 = (tid & 3) << 4;  // transpose mapping

  for (int c = 0; c < NCHUNK; ++c) {
    // ---- P0: stage B, C, X tiles + dt scan ----
    {
      int tdir = c * 64 + srow;
      int rg = bt * LSEQ + (dir ? (LSEQ - 1 - tdir) : tdir);
      const u16* bsrc = bmat + (size_t)rg * 64 + q * 16;
      const u16* csrc = cmat + (size_t)rg * 64 + q * 16;
      const u16* xsrc = xc + (size_t)rg * DINNER + h * 64 + q * 16;
      *(ushort8*)&sB[srow][q * 16] = *(const ushort8*)bsrc;
      *(ushort8*)&sB[srow][q * 16 + 8] = *(const ushort8*)(bsrc + 8);
      *(ushort8*)&sC[srow][q * 16] = *(const ushort8*)csrc;
      *(ushort8*)&sC[srow][q * 16 + 8] = *(const ushort8*)(csrc + 8);
      *(ushort8*)&sXM[srow][q * 16] = *(const ushort8*)xsrc;
      *(ushort8*)&sXM[srow][q * 16 + 8] = *(const ushort8*)(xsrc + 8);
    }
    if (tid < 64) {
      int s = tid;
      float dv = dtp[((size_t)grp * LSEQ + c * 64 + s) * NH + h];
      float a = dv * Ah;
      float x = a;
#pragma unroll
      for (int d = 1; d < 64; d <<= 1) {
        float y = __shfl_up(x, d);
        if (s >= d) x += y;
      }
      float tot = __shfl(x, 63);
      sAc[s] = x;
      sEA[s] = expf(x);
      sSc[s] = expf(tot - x) * dv;  // decay * dt
      sDt[s] = dv;
    }
    __syncthreads();

    // ---- P0b: transpose X and B into row-readable layouts ----
    {
      ushort8 vx0, vx1, vb0, vb1;
#pragma unroll
      for (int i = 0; i < 8; ++i) {
        vx0[i] = sXM[ts0 + i][tp];
        vx1[i] = sXM[ts0 + 8 + i][tp];
        vb0[i] = sB[ts0 + i][tp];
        vb1[i] = sB[ts0 + 8 + i][tp];
      }
      *(ushort8*)&sXT[tp][ts0] = vx0;
      *(ushort8*)&sXT[tp][ts0 + 8] = vx1;
      *(ushort8*)&sBT[tp][ts0] = vb0;
      *(ushort8*)&sBT[tp][ts0 + 8] = vb1;
    }
    __syncthreads();

    // ---- PA: G = C @ B^T -> M (into sXM); Yoff = C @ S_prev^T ----
    f32x4 acc_y[4] = {};
    {
      f32x4 acc_g[4] = {};
#pragma unroll
      for (int ks = 0; ks < 2; ++ks) {
        int kof = ks * 32 + lg * 8;
        short8 af = *(const short8*)&sC[wave * 16 + lr][kof];
#pragma unroll
        for (int nt = 0; nt < 4; ++nt) {
          short8 bf = *(const short8*)&sB[nt * 16 + lr][kof];
          acc_g[nt] = mfma16(af, bf, acc_g[nt]);
        }
      }
#pragma unroll
      for (int ks = 0; ks < 2; ++ks) {
        int kof = ks * 32 + lg * 8;
        short8 af = *(const short8*)&sC[wave * 16 + lr][kof];
#pragma unroll
        for (int nt = 0; nt < 4; ++nt) {
          const float* sr = &sS[nt * 16 + lr][kof];
          f32x4 s0 = *(const f32x4*)sr;
          f32x4 s1 = *(const f32x4*)(sr + 4);
          short8 bf;
#pragma unroll
          for (int e = 0; e < 4; ++e) {
            bf[e] = (short)f2bf(s0[e]);
            bf[e + 4] = (short)f2bf(s1[e]);
          }
          acc_y[nt] = mfma16(af, bf, acc_y[nt]);
        }
      }
      // masked decay matrix M[l][s] -> sXM (sXM's X content is dead: sXT holds it)
#pragma unroll
      for (int nt = 0; nt < 4; ++nt)
#pragma unroll
        for (int rr = 0; rr < 4; ++rr) {
          int l = wave * 16 + lg * 4 + rr;
          int s = nt * 16 + lr;
          float g = acc_g[nt][rr];
          float m = (l >= s) ? g * sDt[s] * expf(sAc[l] - sAc[s]) : 0.f;
          sXM[l][s] = f2bf(m);
        }
    }
    __syncthreads();

    // ---- PB: Y = Yoff*exp(Acum) + M @ X; write Y; S update ----
#pragma unroll
    for (int nt = 0; nt < 4; ++nt)
#pragma unroll
      for (int rr = 0; rr < 4; ++rr) acc_y[nt][rr] *= sEA[wave * 16 + lg * 4 + rr];
#pragma unroll
    for (int ks = 0; ks < 2; ++ks) {
      int kof = ks * 32 + lg * 8;
      short8 af = *(const short8*)&sXM[wave * 16 + lr][kof];
#pragma unroll
      for (int nt = 0; nt < 4; ++nt) {
        short8 bf = *(const short8*)&sXT[nt * 16 + lr][kof];
        acc_y[nt] = mfma16(af, bf, acc_y[nt]);
      }
    }
#pragma unroll
    for (int nt = 0; nt < 4; ++nt)
#pragma unroll
      for (int rr = 0; rr < 4; ++rr) {
        int l = wave * 16 + lg * 4 + rr;
        int p = nt * 16 + lr;
        int tg = c * 64 + l;
        if (tg <= LSEQ - 2) {
          float v = acc_y[nt][rr];
          if (dir == 0)
            y0[((size_t)bt * LSEQ + tg + 1) * DINNER + h * 64 + p] = f2bf(v);
          else
            y1[((size_t)bt * LSEQ + (LSEQ - 2 - tg)) * DINNER + h * 64 + p] = f2bf(v);
        }
      }
    if (c == 0 && tid < 64) {
      if (dir == 0)
        y0[((size_t)bt * LSEQ) * DINNER + h * 64 + tid] = 0;
      else
        y1[((size_t)bt * LSEQ + (LSEQ - 1)) * DINNER + h * 64 + tid] = 0;
    }
    // chunk state: S_new = exp(Asum)*S + (X*decay*dt)^T @ B
    {
      f32x4 acc_s[4] = {};
#pragma unroll
      for (int ks = 0; ks < 2; ++ks) {
        int kof = ks * 32 + lg * 8;
        ushort8 xr = *(const ushort8*)&sXT[wave * 16 + lr][kof];
        short8 af;
#pragma unroll
        for (int e = 0; e < 8; ++e) af[e] = (short)f2bf(bf2f(xr[e]) * sSc[kof + e]);
#pragma unroll
        for (int nt = 0; nt < 4; ++nt) {
          short8 bf = *(const short8*)&sBT[nt * 16 + lr][kof];
          acc_s[nt] = mfma16(af, bf, acc_s[nt]);
        }
      }
      float lam = sEA[63];
#pragma unroll
      for (int nt = 0; nt < 4; ++nt)
#pragma unroll
        for (int rr = 0; rr < 4; ++rr) {
          int p = wave * 16 + lg * 4 + rr;
          int n = nt * 16 + lr;
          sS[p][n] = lam * sS[p][n] + acc_s[nt][rr];
        }
    }
    __syncthreads();
  }
}

// ---------------- Deff = x @ fc_D_w^T + D (LDS-staged, 16 rows/block) ----------------
__global__ __launch_bounds__(256) void k_deff(const u16* __restrict__ xcv,
                                              const float* __restrict__ fw,
                                              const float* __restrict__ Dv,
                                              float* __restrict__ deff) {
  __shared__ u16 sx[16][2064];  // +16 pad: rows land on distinct bank groups
  const int rb = blockIdx.x * 16;
  for (int v = threadIdx.x; v < 4096; v += 256) {
    int r = v >> 8, c = (v & 255) * 8;
    *(ushort8*)&sx[r][c] = *(const ushort8*)(xcv + (size_t)(rb + r) * DINNER + c);
  }
  __syncthreads();
  const int r = threadIdx.x >> 4;
  const int hp = (threadIdx.x & 15) * 2;
  const float* f0 = fw + (size_t)hp * DINNER;
  const float* f1 = f0 + DINNER;
  float a0 = 0.f, a1 = 0.f;
  for (int k = 0; k < DINNER; k += 8) {
    ushort8 xv = *(const ushort8*)&sx[r][k];
    float4 p0 = *(const float4*)(f0 + k);
    float4 p1 = *(const float4*)(f0 + k + 4);
    float4 q0 = *(const float4*)(f1 + k);
    float4 q1 = *(const float4*)(f1 + k + 4);
    a0 += bf2f(xv[0]) * p0.x + bf2f(xv[1]) * p0.y + bf2f(xv[2]) * p0.z + bf2f(xv[3]) * p0.w +
          bf2f(xv[4]) * p1.x + bf2f(xv[5]) * p1.y + bf2f(xv[6]) * p1.z + bf2f(xv[7]) * p1.w;
    a1 += bf2f(xv[0]) * q0.x + bf2f(xv[1]) * q0.y + bf2f(xv[2]) * q0.z + bf2f(xv[3]) * q0.w +
          bf2f(xv[4]) * q1.x + bf2f(xv[5]) * q1.y + bf2f(xv[6]) * q1.z + bf2f(xv[7]) * q1.w;
  }
  deff[(size_t)(rb + r) * NH + hp] = a0 + Dv[hp];
  deff[(size_t)(rb + r) * NH + hp + 1] = a1 + Dv[hp + 1];
}

// ---------------- gating: yn = rmsnorm((y0 + y1 + x*Deff) * silu(z)) * gnw ----------------
__global__ __launch_bounds__(256) void k_gate(const u16* __restrict__ yb0,
                                              const u16* __restrict__ yb1,
                                              const u16* __restrict__ xcv,
                                              const float* __restrict__ deff,
                                              const u16* __restrict__ zb,
                                              const float* __restrict__ gnw,
                                              u16* __restrict__ yn) {
  int row = blockIdx.x, t = threadIdx.x;
  size_t base = (size_t)row * DINNER + t * 8;
  ushort8 y0v = *(const ushort8*)(yb0 + base);
  ushort8 y1v = *(const ushort8*)(yb1 + base);
  ushort8 xv = *(const ushort8*)(xcv + base);
  ushort8 zv = *(const ushort8*)(zb + base);
  float de = deff[row * NH + (t >> 3)];
  float g[8];
  float ss = 0.f;
#pragma unroll
  for (int j = 0; j < 8; ++j) {
    float y = bf2f(y0v[j]) + bf2f(y1v[j]) + bf2f(xv[j]) * de;
    float z = bf2f(zv[j]);
    float gg = y * (z / (1.f + expf(-z)));
    g[j] = gg;
    ss += gg * gg;
  }
  for (int m = 32; m; m >>= 1) ss += __shfl_xor(ss, m);
  __shared__ float wsum[4];
  if ((t & 63) == 0) wsum[t >> 6] = ss;
  __syncthreads();
  float tot = wsum[0] + wsum[1] + wsum[2] + wsum[3];
  float rinv = rsqrtf(tot * (1.0f / DINNER) + 1e-5f);
  u32 w0 = (u32)f2bf(g[0] * rinv * gnw[t * 8 + 0]) | ((u32)f2bf(g[1] * rinv * gnw[t * 8 + 1]) << 16);
  u32 w1 = (u32)f2bf(g[2] * rinv * gnw[t * 8 + 2]) | ((u32)f2bf(g[3] * rinv * gnw[t * 8 + 3]) << 16);
  u32 w2 = (u32)f2bf(g[4] * rinv * gnw[t * 8 + 4]) | ((u32)f2bf(g[5] * rinv * gnw[t * 8 + 5]) << 16);
  u32 w3 = (u32)f2bf(g[6] * rinv * gnw[t * 8 + 6]) | ((u32)f2bf(g[7] * rinv * gnw[t * 8 + 7]) << 16);
  *(uint4*)(yn + base) = make_uint4(w0, w1, w2, w3);
}

extern "C" void kernel_launch(void* const* d_in, const int* in_sizes, int n_in,
                              void* d_out, int out_size, void* d_ws, size_t ws_size,
                              hipStream_t stream) {
  (void)in_sizes; (void)n_in; (void)out_size; (void)ws_size;
  const float* hid = (const float*)d_in[0];
  const float* resin = (const float*)d_in[1];
  const float* nw = (const float*)d_in[2];
  const float* w1 = (const float*)d_in[3];
  const float* cw = (const float*)d_in[4];
  const float* cb = (const float*)d_in[5];
  const float* dtb = (const float*)d_in[6];
  const float* alog = (const float*)d_in[7];
  const float* Dv = (const float*)d_in[8];
  const float* fcw = (const float*)d_in[9];
  const float* gnw = (const float*)d_in[10];
  const float* w2 = (const float*)d_in[11];
  float* out = (float*)d_out;
  float* resout = out + (size_t)ROWS * DMODEL;

  char* ws = (char*)d_ws;
  size_t o = 0;
  auto alloc = [&](size_t bytes) {
    char* p = ws + o;
    o += (bytes + 255) & ~(size_t)255;
    return p;
  };
  u16* W1b = (u16*)alloc((size_t)DIP_PAD * DMODEL * 2);  // 8.9 MB (reused for W2b)
  u16* HN = (u16*)alloc((size_t)ROWS * DMODEL * 2);      // 16.8 MB (reused for YN)
  u16* XBC = (u16*)alloc((size_t)ROWS * CONVD * 2);      // 35.7 MB (reused for YB0)
  u16* ZB = (u16*)alloc((size_t)ROWS * DINNER * 2);      // 33.6 MB
  u16* XC = (u16*)alloc((size_t)ROWS * DINNER * 2);      // 33.6 MB
  u16* BM = (u16*)alloc((size_t)ROWS * 64 * 2);          // 1 MB
  u16* CM = (u16*)alloc((size_t)ROWS * 64 * 2);          // 1 MB
  float* DT = (float*)alloc((size_t)8 * LSEQ * NH * 4);  // 2 MB
  float* DE = (float*)alloc((size_t)ROWS * NH * 4);      // 1 MB
  u16* YB0 = XBC;
  u16* YB1 = (u16*)out;  // out region (33.55 MB) is dead until final GEMM
  u16* W2b = W1b;
  u16* YN = HN;

  k_cast<<<(DIP * DMODEL) / 1024, 256, 0, stream>>>(w1, W1b);
  k_addnorm<<<ROWS, 256, 0, stream>>>(hid, resin, nw, resout, HN);
  k_gemm<0><<<dim3(ROWS / 128, DIP_PAD / 128), 256, 0, stream>>>(HN, W1b, DMODEL, nullptr, ZB,
                                                                 XBC, DT, dtb);
  k_conv<<<(ROWS * 272) / 256, 256, 0, stream>>>(XBC, cw, cb, XC, BM, CM);
  k_ssd<<<256, 256, 0, stream>>>(XC, BM, CM, DT, alog, YB0, YB1);
  k_cast<<<(DMODEL * DINNER) / 1024, 256, 0, stream>>>(w2, W2b);
  k_deff<<<ROWS / 16, 256, 0, stream>>>(XC, fcw, Dv, DE);
  k_gate<<<ROWS, 256, 0, stream>>>(YB0, YB1, XC, DE, ZB, gnw, YN);
  k_gemm<1><<<dim3(ROWS / 128, DMODEL / 128), 256, 0, stream>>>(YN, W2b, DINNER, out, nullptr,
                                                                nullptr, nullptr, nullptr);
}

// Round 5
// 763.983 us; speedup vs baseline: 1.0924x; 1.0924x over previous
//
#include <hip/hip_runtime.h>

typedef __attribute__((ext_vector_type(4))) float f32x4;
typedef __attribute__((ext_vector_type(8))) short short8;
typedef __attribute__((ext_vector_type(8))) unsigned short ushort8;
typedef unsigned short u16;
typedef unsigned int u32;

#define DMODEL 1024
#define DINNER 2048
#define NH     32
#define DIP    4288
#define DIP_PAD 4352
#define CONVD  2176
#define LSEQ   2048
#define ROWS   8192
#define NCHUNK 32

static __device__ __forceinline__ float bf2f(u16 u) {
  u32 x = ((u32)u) << 16;
  return __builtin_bit_cast(float, x);
}
static __device__ __forceinline__ u16 f2bf(float f) {
  u32 x = __builtin_bit_cast(u32, f);
  x += 0x7fffu + ((x >> 16) & 1u);
  return (u16)(x >> 16);
}
static __device__ __forceinline__ f32x4 mfma16(short8 a, short8 b, f32x4 c) {
  return __builtin_amdgcn_mfma_f32_16x16x32_bf16(a, b, c, 0, 0, 0);
}

#define GLDS(gp, lp)                                                     \
  __builtin_amdgcn_global_load_lds(                                     \
      (const __attribute__((address_space(1))) void*)(gp),              \
      (__attribute__((address_space(3))) void*)(lp), 16, 0, 0)

// ---------------- f32 -> bf16 weight cast ----------------
__global__ __launch_bounds__(256) void k_cast(const float* __restrict__ s, u16* __restrict__ d) {
  size_t i = ((size_t)blockIdx.x * 256 + threadIdx.x) * 4;
  float4 v = *(const float4*)(s + i);
  u32 lo = (u32)f2bf(v.x) | ((u32)f2bf(v.y) << 16);
  u32 hi = (u32)f2bf(v.z) | ((u32)f2bf(v.w) << 16);
  *(uint2*)(d + i) = make_uint2(lo, hi);
}

// ---------------- res = h + r ; hnorm = rmsnorm(res)*w (bf16) ----------------
__global__ __launch_bounds__(256) void k_addnorm(const float* __restrict__ h,
                                                 const float* __restrict__ r,
                                                 const float* __restrict__ nw,
                                                 float* __restrict__ res,
                                                 u16* __restrict__ hn) {
  int row = blockIdx.x, t = threadIdx.x;
  const float4* hp = (const float4*)(h + (size_t)row * DMODEL);
  const float4* rp = (const float4*)(r + (size_t)row * DMODEL);
  float4 a = hp[t], b = rp[t];
  float4 s;
  s.x = a.x + b.x; s.y = a.y + b.y; s.z = a.z + b.z; s.w = a.w + b.w;
  ((float4*)(res + (size_t)row * DMODEL))[t] = s;
  float ss = s.x * s.x + s.y * s.y + s.z * s.z + s.w * s.w;
  for (int m = 32; m; m >>= 1) ss += __shfl_xor(ss, m);
  __shared__ float wsum[4];
  if ((t & 63) == 0) wsum[t >> 6] = ss;
  __syncthreads();
  float tot = wsum[0] + wsum[1] + wsum[2] + wsum[3];
  float rinv = rsqrtf(tot * (1.0f / DMODEL) + 1e-5f);
  float4 w4 = ((const float4*)nw)[t];
  u32 lo = (u32)f2bf(s.x * rinv * w4.x) | ((u32)f2bf(s.y * rinv * w4.y) << 16);
  u32 hi = (u32)f2bf(s.z * rinv * w4.z) | ((u32)f2bf(s.w * rinv * w4.w) << 16);
  *(uint2*)(hn + (size_t)row * DMODEL + t * 4) = make_uint2(lo, hi);
}

// ---------------- bf16 MFMA GEMM: 256x128 tile, 8 waves, BK=64, dbuf 96KB ----------------
// Waves 4(M)x2(N): wave owns 64x64 out = 4x4 mfma_16x16x32 frags, acc over 2 k-steps.
// Per K-tile: STAGE(t+1) [6 GLDS] -> vmcnt(6) -> barrier -> 16x ds_read_b128 (XOR-swizzled)
// -> lgkmcnt(0) -> barrier -> setprio(1) 32 MFMA setprio(0).
// Swizzle (both-sides involution, T21): byte ^= ((byte>>7)&7)<<4 within each tile.
template <int MODE>
__global__ __launch_bounds__(512) void k_gemm(const u16* __restrict__ A,
                                              const u16* __restrict__ Bw, int K,
                                              float* __restrict__ outf,
                                              u16* __restrict__ zb, u16* __restrict__ xb,
                                              float* __restrict__ dtp,
                                              const float* __restrict__ dt_bias) {
  __shared__ char lds[98304];  // 2 x (A 32KB + B 16KB)
  const int tid = threadIdx.x, wave = tid >> 6, lane = tid & 63;
  const int wm = wave >> 1, wn = wave & 1;
  const int lr = lane & 15, lg = lane >> 4;
  const int brow = blockIdx.x * 256, bcol = blockIdx.y * 128;
  const int NK = K >> 6;

  // staging: per-thread pre-swizzled global source offsets (element units)
  size_t srcA[4], srcB[2];
#pragma unroll
  for (int g = 0; g < 4; ++g) {
    int d = g * 8192 + tid * 16;
    int s = d ^ (((d >> 7) & 7) << 4);
    srcA[g] = (size_t)(brow + (s >> 7)) * K + ((s & 127) >> 1);
  }
#pragma unroll
  for (int g = 0; g < 2; ++g) {
    int d = g * 8192 + tid * 16;
    int s = d ^ (((d >> 7) & 7) << 4);
    srcB[g] = (size_t)(bcol + (s >> 7)) * K + ((s & 127) >> 1);
  }

  auto STAGE = [&](int buf, int kt) {
    char* base = lds + buf * 49152;
    size_t koff = (size_t)kt * 64;
#pragma unroll
    for (int g = 0; g < 4; ++g)
      GLDS(A + srcA[g] + koff, base + g * 8192 + wave * 1024);
#pragma unroll
    for (int g = 0; g < 2; ++g)
      GLDS(Bw + srcB[g] + koff, base + 32768 + g * 8192 + wave * 1024);
  };

  // swizzled ds_read byte offsets (row&7 == lr&7 since row base is a multiple of 8)
  int offA[4][2], offB[4][2];
#pragma unroll
  for (int i = 0; i < 4; ++i)
#pragma unroll
    for (int ks = 0; ks < 2; ++ks) {
      int rA = wm * 64 + i * 16 + lr;
      int bA = rA * 128 + ks * 64 + lg * 16;
      offA[i][ks] = bA ^ ((lr & 7) << 4);
      int rB = wn * 64 + i * 16 + lr;
      int bB = rB * 128 + ks * 64 + lg * 16;
      offB[i][ks] = 32768 + (bB ^ ((lr & 7) << 4));
    }

  f32x4 acc[4][4] = {};
  STAGE(0, 0);
  for (int t = 0; t < NK; ++t) {
    const int cur = t & 1;
    if (t + 1 < NK) {
      STAGE(cur ^ 1, t + 1);
      asm volatile("s_waitcnt vmcnt(6)" ::: "memory");
    } else {
      asm volatile("s_waitcnt vmcnt(0)" ::: "memory");
    }
    __builtin_amdgcn_sched_barrier(0);
    __builtin_amdgcn_s_barrier();
    __builtin_amdgcn_sched_barrier(0);
    const char* bb = lds + cur * 49152;
    short8 af[4][2], bf[4][2];
#pragma unroll
    for (int i = 0; i < 4; ++i)
#pragma unroll
      for (int ks = 0; ks < 2; ++ks) {
        af[i][ks] = *(const short8*)(bb + offA[i][ks]);
        bf[i][ks] = *(const short8*)(bb + offB[i][ks]);
      }
    asm volatile("s_waitcnt lgkmcnt(0)" ::: "memory");
    __builtin_amdgcn_sched_barrier(0);
    __builtin_amdgcn_s_barrier();
    __builtin_amdgcn_sched_barrier(0);
    __builtin_amdgcn_s_setprio(1);
#pragma unroll
    for (int ks = 0; ks < 2; ++ks)
#pragma unroll
      for (int i = 0; i < 4; ++i)
#pragma unroll
        for (int j = 0; j < 4; ++j) acc[i][j] = mfma16(af[i][ks], bf[j][ks], acc[i][j]);
    __builtin_amdgcn_s_setprio(0);
    __builtin_amdgcn_sched_barrier(0);
  }

  const int mb = brow + wm * 64 + lg * 4;
  const int nb = bcol + wn * 64 + lr;
#pragma unroll
  for (int i = 0; i < 4; ++i)
#pragma unroll
    for (int j = 0; j < 4; ++j)
#pragma unroll
      for (int rr = 0; rr < 4; ++rr) {
        int m = mb + i * 16 + rr;
        int n = nb + j * 16;
        float v = acc[i][j][rr];
        if constexpr (MODE == 1) {
          outf[(size_t)m * 1024 + n] = v;
        } else {
          if (n < DINNER) {
            zb[(size_t)m * DINNER + n] = f2bf(v);
          } else if (n < DINNER + CONVD) {
            xb[(size_t)m * CONVD + (n - DINNER)] = f2bf(v);
          } else if (n < DIP) {
            int h2 = n - (DINNER + CONVD);  // 0..63
            float uu = v + dt_bias[h2 & 31];
            float sp = (uu > 20.f) ? uu : log1pf(expf(uu));
            int bb2 = m >> 11, tt = m & 2047;
            int obb = bb2, ot = tt;
            if (h2 >= 32) { obb = bb2 + 4; ot = 2047 - tt; }
            dtp[((size_t)(obb << 11) + ot) * NH + (h2 & 31)] = sp;
          }
        }
      }
}

// ---------------- depthwise causal conv (k=4) + SiLU, 8 chans/thread ----------------
__global__ __launch_bounds__(256) void k_conv(const u16* __restrict__ xbc,
                                              const float* __restrict__ cw,
                                              const float* __restrict__ cb,
                                              u16* __restrict__ xc, u16* __restrict__ bm,
                                              u16* __restrict__ cm) {
  int e = blockIdx.x * 256 + threadIdx.x;  // e < ROWS*272
  int c8 = e % 272;
  int r = e / 272;
  int c = c8 * 8;
  int b = r >> 11, t = r & 2047;
  float4 w[8];
  float a[8];
#pragma unroll
  for (int j = 0; j < 8; ++j) {
    w[j] = *(const float4*)&cw[(c + j) * 4];
    a[j] = cb[c + j];
  }
  const u16* base = xbc + (size_t)(b << 11) * CONVD + c;
#pragma unroll
  for (int k = 0; k < 4; ++k) {
    int tt = t - 3 + k;
    if (tt >= 0) {
      ushort8 v = *(const ushort8*)(base + (size_t)tt * CONVD);
#pragma unroll
      for (int j = 0; j < 8; ++j) a[j] += bf2f(v[j]) * ((const float*)&w[j])[k];
    }
  }
  ushort8 o;
#pragma unroll
  for (int j = 0; j < 8; ++j) {
    float s = a[j] * (1.f / (1.f + expf(-a[j])));
    o[j] = f2bf(s);
  }
  if (c8 < 256) *(ushort8*)(xc + (size_t)r * DINNER + c) = o;
  else if (c8 < 264) *(ushort8*)(bm + (size_t)r * 64 + (c - DINNER)) = o;
  else *(ushort8*)(cm + (size_t)r * 64 + (c - DINNER - 64)) = o;
}

// ---------------- fused SSD scan: one block per (dir, batch, head) ----------------
__global__ __launch_bounds__(256) void k_ssd(const u16* __restrict__ xc,
                                             const u16* __restrict__ bmat,
                                             const u16* __restrict__ cmat,
                                             const float* __restrict__ dtp,
                                             const float* __restrict__ alog,
                                             u16* __restrict__ y0, u16* __restrict__ y1) {
  const int h = blockIdx.x & 31;
  const int grp = blockIdx.x >> 5;  // 0..7
  const int dir = grp >> 2;
  const int bt = grp & 3;
  const int tid = threadIdx.x, wave = tid >> 6, lane = tid & 63;
  const float Ah = -expf(alog[h]);

  __shared__ u16 sB[64][72];   // [s][n]
  __shared__ u16 sC[64][72];   // [s][n]
  __shared__ u16 sXM[64][72];  // staged X [s][p]; after transpose reused as M [l][s]
  __shared__ u16 sXT[64][72];  // X^T [p][s]
  __shared__ u16 sBT[64][72];  // B^T [n][s]
  __shared__ float sS[64][68]; // [p][n] running inter-chunk state (f32)
  __shared__ float sAc[64], sEA[64], sSc[64], sDt[64];

  for (int i = tid; i < 64 * 64; i += 256) sS[i >> 6][i & 63] = 0.f;

  const int lr = lane & 15, lg = lane >> 4;
  const int srow = tid >> 2, q = tid & 3;
  const int tp = tid >> 2, ts0 = (tid & 3) << 4;  // transpose mapping

  for (int c = 0; c < NCHUNK; ++c) {
    // ---- P0: stage B, C, X tiles + dt scan ----
    {
      int tdir = c * 64 + srow;
      int rg = bt * LSEQ + (dir ? (LSEQ - 1 - tdir) : tdir);
      const u16* bsrc = bmat + (size_t)rg * 64 + q * 16;
      const u16* csrc = cmat + (size_t)rg * 64 + q * 16;
      const u16* xsrc = xc + (size_t)rg * DINNER + h * 64 + q * 16;
      *(ushort8*)&sB[srow][q * 16] = *(const ushort8*)bsrc;
      *(ushort8*)&sB[srow][q * 16 + 8] = *(const ushort8*)(bsrc + 8);
      *(ushort8*)&sC[srow][q * 16] = *(const ushort8*)csrc;
      *(ushort8*)&sC[srow][q * 16 + 8] = *(const ushort8*)(csrc + 8);
      *(ushort8*)&sXM[srow][q * 16] = *(const ushort8*)xsrc;
      *(ushort8*)&sXM[srow][q * 16 + 8] = *(const ushort8*)(xsrc + 8);
    }
    if (tid < 64) {
      int s = tid;
      float dv = dtp[((size_t)grp * LSEQ + c * 64 + s) * NH + h];
      float a = dv * Ah;
      float x = a;
#pragma unroll
      for (int d = 1; d < 64; d <<= 1) {
        float y = __shfl_up(x, d);
        if (s >= d) x += y;
      }
      float tot = __shfl(x, 63);
      sAc[s] = x;
      sEA[s] = expf(x);
      sSc[s] = expf(tot - x) * dv;  // decay * dt
      sDt[s] = dv;
    }
    __syncthreads();

    // ---- P0b: transpose X and B into row-readable layouts ----
    {
      ushort8 vx0, vx1, vb0, vb1;
#pragma unroll
      for (int i = 0; i < 8; ++i) {
        vx0[i] = sXM[ts0 + i][tp];
        vx1[i] = sXM[ts0 + 8 + i][tp];
        vb0[i] = sB[ts0 + i][tp];
        vb1[i] = sB[ts0 + 8 + i][tp];
      }
      *(ushort8*)&sXT[tp][ts0] = vx0;
      *(ushort8*)&sXT[tp][ts0 + 8] = vx1;
      *(ushort8*)&sBT[tp][ts0] = vb0;
      *(ushort8*)&sBT[tp][ts0 + 8] = vb1;
    }
    __syncthreads();

    // ---- PA: G = C @ B^T -> M (into sXM); Yoff = C @ S_prev^T ----
    f32x4 acc_y[4] = {};
    {
      f32x4 acc_g[4] = {};
#pragma unroll
      for (int ks = 0; ks < 2; ++ks) {
        int kof = ks * 32 + lg * 8;
        short8 af = *(const short8*)&sC[wave * 16 + lr][kof];
#pragma unroll
        for (int nt = 0; nt < 4; ++nt) {
          short8 bf = *(const short8*)&sB[nt * 16 + lr][kof];
          acc_g[nt] = mfma16(af, bf, acc_g[nt]);
        }
      }
#pragma unroll
      for (int ks = 0; ks < 2; ++ks) {
        int kof = ks * 32 + lg * 8;
        short8 af = *(const short8*)&sC[wave * 16 + lr][kof];
#pragma unroll
        for (int nt = 0; nt < 4; ++nt) {
          const float* sr = &sS[nt * 16 + lr][kof];
          f32x4 s0 = *(const f32x4*)sr;
          f32x4 s1 = *(const f32x4*)(sr + 4);
          short8 bf;
#pragma unroll
          for (int e = 0; e < 4; ++e) {
            bf[e] = (short)f2bf(s0[e]);
            bf[e + 4] = (short)f2bf(s1[e]);
          }
          acc_y[nt] = mfma16(af, bf, acc_y[nt]);
        }
      }
      // masked decay matrix M[l][s] -> sXM (sXM's X content is dead: sXT holds it)
#pragma unroll
      for (int nt = 0; nt < 4; ++nt)
#pragma unroll
        for (int rr = 0; rr < 4; ++rr) {
          int l = wave * 16 + lg * 4 + rr;
          int s = nt * 16 + lr;
          float g = acc_g[nt][rr];
          float m = (l >= s) ? g * sDt[s] * expf(sAc[l] - sAc[s]) : 0.f;
          sXM[l][s] = f2bf(m);
        }
    }
    __syncthreads();

    // ---- PB: Y = Yoff*exp(Acum) + M @ X; write Y; S update ----
#pragma unroll
    for (int nt = 0; nt < 4; ++nt)
#pragma unroll
      for (int rr = 0; rr < 4; ++rr) acc_y[nt][rr] *= sEA[wave * 16 + lg * 4 + rr];
#pragma unroll
    for (int ks = 0; ks < 2; ++ks) {
      int kof = ks * 32 + lg * 8;
      short8 af = *(const short8*)&sXM[wave * 16 + lr][kof];
#pragma unroll
      for (int nt = 0; nt < 4; ++nt) {
        short8 bf = *(const short8*)&sXT[nt * 16 + lr][kof];
        acc_y[nt] = mfma16(af, bf, acc_y[nt]);
      }
    }
#pragma unroll
    for (int nt = 0; nt < 4; ++nt)
#pragma unroll
      for (int rr = 0; rr < 4; ++rr) {
        int l = wave * 16 + lg * 4 + rr;
        int p = nt * 16 + lr;
        int tg = c * 64 + l;
        if (tg <= LSEQ - 2) {
          float v = acc_y[nt][rr];
          if (dir == 0)
            y0[((size_t)bt * LSEQ + tg + 1) * DINNER + h * 64 + p] = f2bf(v);
          else
            y1[((size_t)bt * LSEQ + (LSEQ - 2 - tg)) * DINNER + h * 64 + p] = f2bf(v);
        }
      }
    if (c == 0 && tid < 64) {
      if (dir == 0)
        y0[((size_t)bt * LSEQ) * DINNER + h * 64 + tid] = 0;
      else
        y1[((size_t)bt * LSEQ + (LSEQ - 1)) * DINNER + h * 64 + tid] = 0;
    }
    // chunk state: S_new = exp(Asum)*S + (X*decay*dt)^T @ B
    {
      f32x4 acc_s[4] = {};
#pragma unroll
      for (int ks = 0; ks < 2; ++ks) {
        int kof = ks * 32 + lg * 8;
        ushort8 xr = *(const ushort8*)&sXT[wave * 16 + lr][kof];
        short8 af;
#pragma unroll
        for (int e = 0; e < 8; ++e) af[e] = (short)f2bf(bf2f(xr[e]) * sSc[kof + e]);
#pragma unroll
        for (int nt = 0; nt < 4; ++nt) {
          short8 bf = *(const short8*)&sBT[nt * 16 + lr][kof];
          acc_s[nt] = mfma16(af, bf, acc_s[nt]);
        }
      }
      float lam = sEA[63];
#pragma unroll
      for (int nt = 0; nt < 4; ++nt)
#pragma unroll
        for (int rr = 0; rr < 4; ++rr) {
          int p = wave * 16 + lg * 4 + rr;
          int n = nt * 16 + lr;
          sS[p][n] = lam * sS[p][n] + acc_s[nt][rr];
        }
    }
    __syncthreads();
  }
}

// ---------------- Deff = x @ fc_D_w^T + D (LDS-staged, 16 rows/block) ----------------
__global__ __launch_bounds__(256) void k_deff(const u16* __restrict__ xcv,
                                              const float* __restrict__ fw,
                                              const float* __restrict__ Dv,
                                              float* __restrict__ deff) {
  __shared__ u16 sx[16][2064];  // +16 pad: rows land on distinct bank groups
  const int rb = blockIdx.x * 16;
  for (int v = threadIdx.x; v < 4096; v += 256) {
    int r = v >> 8, c = (v & 255) * 8;
    *(ushort8*)&sx[r][c] = *(const ushort8*)(xcv + (size_t)(rb + r) * DINNER + c);
  }
  __syncthreads();
  const int r = threadIdx.x >> 4;
  const int hp = (threadIdx.x & 15) * 2;
  const float* f0 = fw + (size_t)hp * DINNER;
  const float* f1 = f0 + DINNER;
  float a0 = 0.f, a1 = 0.f;
  for (int k = 0; k < DINNER; k += 8) {
    ushort8 xv = *(const ushort8*)&sx[r][k];
    float4 p0 = *(const float4*)(f0 + k);
    float4 p1 = *(const float4*)(f0 + k + 4);
    float4 q0 = *(const float4*)(f1 + k);
    float4 q1 = *(const float4*)(f1 + k + 4);
    a0 += bf2f(xv[0]) * p0.x + bf2f(xv[1]) * p0.y + bf2f(xv[2]) * p0.z + bf2f(xv[3]) * p0.w +
          bf2f(xv[4]) * p1.x + bf2f(xv[5]) * p1.y + bf2f(xv[6]) * p1.z + bf2f(xv[7]) * p1.w;
    a1 += bf2f(xv[0]) * q0.x + bf2f(xv[1]) * q0.y + bf2f(xv[2]) * q0.z + bf2f(xv[3]) * q0.w +
          bf2f(xv[4]) * q1.x + bf2f(xv[5]) * q1.y + bf2f(xv[6]) * q1.z + bf2f(xv[7]) * q1.w;
  }
  deff[(size_t)(rb + r) * NH + hp] = a0 + Dv[hp];
  deff[(size_t)(rb + r) * NH + hp + 1] = a1 + Dv[hp + 1];
}

// ---------------- gating: yn = rmsnorm((y0 + y1 + x*Deff) * silu(z)) * gnw ----------------
__global__ __launch_bounds__(256) void k_gate(const u16* __restrict__ yb0,
                                              const u16* __restrict__ yb1,
                                              const u16* __restrict__ xcv,
                                              const float* __restrict__ deff,
                                              const u16* __restrict__ zb,
                                              const float* __restrict__ gnw,
                                              u16* __restrict__ yn) {
  int row = blockIdx.x, t = threadIdx.x;
  size_t base = (size_t)row * DINNER + t * 8;
  ushort8 y0v = *(const ushort8*)(yb0 + base);
  ushort8 y1v = *(const ushort8*)(yb1 + base);
  ushort8 xv = *(const ushort8*)(xcv + base);
  ushort8 zv = *(const ushort8*)(zb + base);
  float de = deff[row * NH + (t >> 3)];
  float g[8];
  float ss = 0.f;
#pragma unroll
  for (int j = 0; j < 8; ++j) {
    float y = bf2f(y0v[j]) + bf2f(y1v[j]) + bf2f(xv[j]) * de;
    float z = bf2f(zv[j]);
    float gg = y * (z / (1.f + expf(-z)));
    g[j] = gg;
    ss += gg * gg;
  }
  for (int m = 32; m; m >>= 1) ss += __shfl_xor(ss, m);
  __shared__ float wsum[4];
  if ((t & 63) == 0) wsum[t >> 6] = ss;
  __syncthreads();
  float tot = wsum[0] + wsum[1] + wsum[2] + wsum[3];
  float rinv = rsqrtf(tot * (1.0f / DINNER) + 1e-5f);
  u32 w0 = (u32)f2bf(g[0] * rinv * gnw[t * 8 + 0]) | ((u32)f2bf(g[1] * rinv * gnw[t * 8 + 1]) << 16);
  u32 w1 = (u32)f2bf(g[2] * rinv * gnw[t * 8 + 2]) | ((u32)f2bf(g[3] * rinv * gnw[t * 8 + 3]) << 16);
  u32 w2 = (u32)f2bf(g[4] * rinv * gnw[t * 8 + 4]) | ((u32)f2bf(g[5] * rinv * gnw[t * 8 + 5]) << 16);
  u32 w3 = (u32)f2bf(g[6] * rinv * gnw[t * 8 + 6]) | ((u32)f2bf(g[7] * rinv * gnw[t * 8 + 7]) << 16);
  *(uint4*)(yn + base) = make_uint4(w0, w1, w2, w3);
}

extern "C" void kernel_launch(void* const* d_in, const int* in_sizes, int n_in,
                              void* d_out, int out_size, void* d_ws, size_t ws_size,
                              hipStream_t stream) {
  (void)in_sizes; (void)n_in; (void)out_size; (void)ws_size;
  const float* hid = (const float*)d_in[0];
  const float* resin = (const float*)d_in[1];
  const float* nw = (const float*)d_in[2];
  const float* w1 = (const float*)d_in[3];
  const float* cw = (const float*)d_in[4];
  const float* cb = (const float*)d_in[5];
  const float* dtb = (const float*)d_in[6];
  const float* alog = (const float*)d_in[7];
  const float* Dv = (const float*)d_in[8];
  const float* fcw = (const float*)d_in[9];
  const float* gnw = (const float*)d_in[10];
  const float* w2 = (const float*)d_in[11];
  float* out = (float*)d_out;
  float* resout = out + (size_t)ROWS * DMODEL;

  char* ws = (char*)d_ws;
  size_t o = 0;
  auto alloc = [&](size_t bytes) {
    char* p = ws + o;
    o += (bytes + 255) & ~(size_t)255;
    return p;
  };
  u16* W1b = (u16*)alloc((size_t)DIP_PAD * DMODEL * 2);  // 8.9 MB (reused for W2b)
  u16* HN = (u16*)alloc((size_t)ROWS * DMODEL * 2);      // 16.8 MB (reused for YN)
  u16* XBC = (u16*)alloc((size_t)ROWS * CONVD * 2);      // 35.7 MB (reused for YB0)
  u16* ZB = (u16*)alloc((size_t)ROWS * DINNER * 2);      // 33.6 MB
  u16* XC = (u16*)alloc((size_t)ROWS * DINNER * 2);      // 33.6 MB
  u16* BM = (u16*)alloc((size_t)ROWS * 64 * 2);          // 1 MB
  u16* CM = (u16*)alloc((size_t)ROWS * 64 * 2);          // 1 MB
  float* DT = (float*)alloc((size_t)8 * LSEQ * NH * 4);  // 2 MB
  float* DE = (float*)alloc((size_t)ROWS * NH * 4);      // 1 MB
  u16* YB0 = XBC;
  u16* YB1 = (u16*)out;  // out region (33.55 MB) is dead until final GEMM
  u16* W2b = W1b;
  u16* YN = HN;

  k_cast<<<(DIP * DMODEL) / 1024, 256, 0, stream>>>(w1, W1b);
  k_addnorm<<<ROWS, 256, 0, stream>>>(hid, resin, nw, resout, HN);
  k_gemm<0><<<dim3(ROWS / 256, DIP_PAD / 128), 512, 0, stream>>>(HN, W1b, DMODEL, nullptr, ZB,
                                                                 XBC, DT, dtb);
  k_conv<<<(ROWS * 272) / 256, 256, 0, stream>>>(XBC, cw, cb, XC, BM, CM);
  k_ssd<<<256, 256, 0, stream>>>(XC, BM, CM, DT, alog, YB0, YB1);
  k_cast<<<(DMODEL * DINNER) / 1024, 256, 0, stream>>>(w2, W2b);
  k_deff<<<ROWS / 16, 256, 0, stream>>>(XC, fcw, Dv, DE);
  k_gate<<<ROWS, 256, 0, stream>>>(YB0, YB1, XC, DE, ZB, gnw, YN);
  k_gemm<1><<<dim3(ROWS / 256, DMODEL / 128), 512, 0, stream>>>(YN, W2b, DINNER, out, nullptr,
                                                                nullptr, nullptr, nullptr);
}

// Round 6
// 744.968 us; speedup vs baseline: 1.1202x; 1.0255x over previous
//
#include <hip/hip_runtime.h>

typedef __attribute__((ext_vector_type(4))) float f32x4;
typedef __attribute__((ext_vector_type(8))) short short8;
typedef __attribute__((ext_vector_type(8))) unsigned short ushort8;
typedef unsigned short u16;
typedef unsigned int u32;

#define DMODEL 1024
#define DINNER 2048
#define NH     32
#define DIP    4288
#define DIP_PAD 4352
#define CONVD  2176
#define LSEQ   2048
#define ROWS   8192
#define NCHUNK 32

static __device__ __forceinline__ float bf2f(u16 u) {
  u32 x = ((u32)u) << 16;
  return __builtin_bit_cast(float, x);
}
static __device__ __forceinline__ u16 f2bf(float f) {
  u32 x = __builtin_bit_cast(u32, f);
  x += 0x7fffu + ((x >> 16) & 1u);
  return (u16)(x >> 16);
}
static __device__ __forceinline__ f32x4 mfma16(short8 a, short8 b, f32x4 c) {
  return __builtin_amdgcn_mfma_f32_16x16x32_bf16(a, b, c, 0, 0, 0);
}

#define GLDS(gp, lp)                                                     \
  __builtin_amdgcn_global_load_lds(                                     \
      (const __attribute__((address_space(1))) void*)(gp),              \
      (__attribute__((address_space(3))) void*)(lp), 16, 0, 0)

// ---------------- f32 -> bf16 weight cast ----------------
__global__ __launch_bounds__(256) void k_cast(const float* __restrict__ s, u16* __restrict__ d) {
  size_t i = ((size_t)blockIdx.x * 256 + threadIdx.x) * 4;
  float4 v = *(const float4*)(s + i);
  u32 lo = (u32)f2bf(v.x) | ((u32)f2bf(v.y) << 16);
  u32 hi = (u32)f2bf(v.z) | ((u32)f2bf(v.w) << 16);
  *(uint2*)(d + i) = make_uint2(lo, hi);
}

// ---------------- res = h + r ; hnorm = rmsnorm(res)*w (bf16) ----------------
__global__ __launch_bounds__(256) void k_addnorm(const float* __restrict__ h,
                                                 const float* __restrict__ r,
                                                 const float* __restrict__ nw,
                                                 float* __restrict__ res,
                                                 u16* __restrict__ hn) {
  int row = blockIdx.x, t = threadIdx.x;
  const float4* hp = (const float4*)(h + (size_t)row * DMODEL);
  const float4* rp = (const float4*)(r + (size_t)row * DMODEL);
  float4 a = hp[t], b = rp[t];
  float4 s;
  s.x = a.x + b.x; s.y = a.y + b.y; s.z = a.z + b.z; s.w = a.w + b.w;
  ((float4*)(res + (size_t)row * DMODEL))[t] = s;
  float ss = s.x * s.x + s.y * s.y + s.z * s.z + s.w * s.w;
  for (int m = 32; m; m >>= 1) ss += __shfl_xor(ss, m);
  __shared__ float wsum[4];
  if ((t & 63) == 0) wsum[t >> 6] = ss;
  __syncthreads();
  float tot = wsum[0] + wsum[1] + wsum[2] + wsum[3];
  float rinv = rsqrtf(tot * (1.0f / DMODEL) + 1e-5f);
  float4 w4 = ((const float4*)nw)[t];
  u32 lo = (u32)f2bf(s.x * rinv * w4.x) | ((u32)f2bf(s.y * rinv * w4.y) << 16);
  u32 hi = (u32)f2bf(s.z * rinv * w4.z) | ((u32)f2bf(s.w * rinv * w4.w) << 16);
  *(uint2*)(hn + (size_t)row * DMODEL + t * 4) = make_uint2(lo, hi);
}

// ---------------- bf16 MFMA GEMM: 128x256 tile, 8 waves, BK=64, 2-phase 1-barrier ----------------
// T3 "minimum 2-phase": STAGE(next) -> ds_read(cur) -> MFMA -> vmcnt(0) -> barrier.
// One barrier/iter: waves' LDS-read and MFMA phases overlap; staged loads hide
// under the full compute phase. XOR-swizzle (verified: 0 conflicts) on both sides.
// XCD-bijective block remap, A-panel-resident order (bx = wg/nN).
template <int MODE>
__global__ __launch_bounds__(512) void k_gemm(const u16* __restrict__ A,
                                              const u16* __restrict__ Bw, int K, int nN,
                                              float* __restrict__ outf,
                                              u16* __restrict__ zb, u16* __restrict__ xb,
                                              float* __restrict__ dtp,
                                              const float* __restrict__ dt_bias) {
  constexpr int ABY = 128 * 64 * 2;   // 16 KB A tile
  constexpr int BBY = 256 * 64 * 2;   // 32 KB B tile
  constexpr int TB = ABY + BBY;       // 48 KB per buffer
  __shared__ char lds[2 * TB];

  const int tid = threadIdx.x, wave = tid >> 6, lane = tid & 63;
  const int wm = wave >> 2, wn = wave & 3;
  const int lr = lane & 15, lg = lane >> 4;

  // XCD-bijective remap (gridDim.x % 8 == 0), A-panel-resident ordering
  const int cpx = gridDim.x >> 3;
  const int orig = blockIdx.x;
  const int wg = (orig & 7) * cpx + (orig >> 3);
  const int brow = (wg / nN) * 128;
  const int bcol = (wg % nN) * 256;
  const int NK = K >> 6;

  size_t srcA[2], srcB[4];
#pragma unroll
  for (int g = 0; g < 2; ++g) {
    int d = g * 8192 + tid * 16;
    int s = d ^ (((d >> 7) & 7) << 4);
    srcA[g] = (size_t)(brow + (s >> 7)) * K + ((s & 127) >> 1);
  }
#pragma unroll
  for (int g = 0; g < 4; ++g) {
    int d = g * 8192 + tid * 16;
    int s = d ^ (((d >> 7) & 7) << 4);
    srcB[g] = (size_t)(bcol + (s >> 7)) * K + ((s & 127) >> 1);
  }

  auto STAGE = [&](int buf, int kt) {
    char* base = lds + buf * TB;
    size_t koff = (size_t)kt * 64;
#pragma unroll
    for (int g = 0; g < 2; ++g)
      GLDS(A + srcA[g] + koff, base + g * 8192 + wave * 1024);
#pragma unroll
    for (int g = 0; g < 4; ++g)
      GLDS(Bw + srcB[g] + koff, base + ABY + g * 8192 + wave * 1024);
  };

  int offA[4][2], offB[4][2];
#pragma unroll
  for (int i = 0; i < 4; ++i)
#pragma unroll
    for (int ks = 0; ks < 2; ++ks) {
      int rA = wm * 64 + i * 16 + lr;
      offA[i][ks] = (rA * 128 + ks * 64 + lg * 16) ^ ((lr & 7) << 4);
      int rB = wn * 64 + i * 16 + lr;
      offB[i][ks] = ABY + ((rB * 128 + ks * 64 + lg * 16) ^ ((lr & 7) << 4));
    }

  f32x4 acc[4][4] = {};
  STAGE(0, 0);
  asm volatile("s_waitcnt vmcnt(0)" ::: "memory");
  __builtin_amdgcn_s_barrier();
  for (int t = 0; t < NK; ++t) {
    const int cur = t & 1;
    if (t + 1 < NK) STAGE(cur ^ 1, t + 1);
    const char* bb = lds + cur * TB;
    short8 af[4], bfr[4];
#pragma unroll
    for (int i = 0; i < 4; ++i) af[i] = *(const short8*)(bb + offA[i][0]);
#pragma unroll
    for (int j = 0; j < 4; ++j) bfr[j] = *(const short8*)(bb + offB[j][0]);
    __builtin_amdgcn_s_setprio(1);
#pragma unroll
    for (int i = 0; i < 4; ++i)
#pragma unroll
      for (int j = 0; j < 4; ++j) acc[i][j] = mfma16(af[i], bfr[j], acc[i][j]);
    __builtin_amdgcn_s_setprio(0);
#pragma unroll
    for (int i = 0; i < 4; ++i) af[i] = *(const short8*)(bb + offA[i][1]);
#pragma unroll
    for (int j = 0; j < 4; ++j) bfr[j] = *(const short8*)(bb + offB[j][1]);
    __builtin_amdgcn_s_setprio(1);
#pragma unroll
    for (int i = 0; i < 4; ++i)
#pragma unroll
      for (int j = 0; j < 4; ++j) acc[i][j] = mfma16(af[i], bfr[j], acc[i][j]);
    __builtin_amdgcn_s_setprio(0);
    if (t + 1 < NK) {
      asm volatile("s_waitcnt vmcnt(0)" ::: "memory");
      __builtin_amdgcn_s_barrier();
    }
  }

  const int mb = brow + wm * 64 + lg * 4;
  const int nb = bcol + wn * 64 + lr;
#pragma unroll
  for (int i = 0; i < 4; ++i)
#pragma unroll
    for (int j = 0; j < 4; ++j)
#pragma unroll
      for (int rr = 0; rr < 4; ++rr) {
        int m = mb + i * 16 + rr;
        int n = nb + j * 16;
        float v = acc[i][j][rr];
        if constexpr (MODE == 1) {
          outf[(size_t)m * 1024 + n] = v;
        } else {
          if (n < DINNER) {
            zb[(size_t)m * DINNER + n] = f2bf(v);
          } else if (n < DINNER + CONVD) {
            xb[(size_t)m * CONVD + (n - DINNER)] = f2bf(v);
          } else if (n < DIP) {
            int h2 = n - (DINNER + CONVD);  // 0..63
            float uu = v + dt_bias[h2 & 31];
            float sp = (uu > 20.f) ? uu : log1pf(expf(uu));
            int bb2 = m >> 11, tt = m & 2047;
            int obb = bb2, ot = tt;
            if (h2 >= 32) { obb = bb2 + 4; ot = 2047 - tt; }
            dtp[((size_t)(obb << 11) + ot) * NH + (h2 & 31)] = sp;
          }
        }
      }
}

// ---------------- depthwise causal conv (k=4) + SiLU, 8 chans/thread ----------------
__global__ __launch_bounds__(256) void k_conv(const u16* __restrict__ xbc,
                                              const float* __restrict__ cw,
                                              const float* __restrict__ cb,
                                              u16* __restrict__ xc, u16* __restrict__ bm,
                                              u16* __restrict__ cm) {
  int e = blockIdx.x * 256 + threadIdx.x;  // e < ROWS*272
  int c8 = e % 272;
  int r = e / 272;
  int c = c8 * 8;
  int b = r >> 11, t = r & 2047;
  float4 w[8];
  float a[8];
#pragma unroll
  for (int j = 0; j < 8; ++j) {
    w[j] = *(const float4*)&cw[(c + j) * 4];
    a[j] = cb[c + j];
  }
  const u16* base = xbc + (size_t)(b << 11) * CONVD + c;
#pragma unroll
  for (int k = 0; k < 4; ++k) {
    int tt = t - 3 + k;
    if (tt >= 0) {
      ushort8 v = *(const ushort8*)(base + (size_t)tt * CONVD);
#pragma unroll
      for (int j = 0; j < 8; ++j) a[j] += bf2f(v[j]) * ((const float*)&w[j])[k];
    }
  }
  ushort8 o;
#pragma unroll
  for (int j = 0; j < 8; ++j) {
    float s = a[j] * (1.f / (1.f + expf(-a[j])));
    o[j] = f2bf(s);
  }
  if (c8 < 256) *(ushort8*)(xc + (size_t)r * DINNER + c) = o;
  else if (c8 < 264) *(ushort8*)(bm + (size_t)r * 64 + (c - DINNER)) = o;
  else *(ushort8*)(cm + (size_t)r * 64 + (c - DINNER - 64)) = o;
}

// ---------------- fused SSD scan: one block per (dir, batch, head) ----------------
__global__ __launch_bounds__(256) void k_ssd(const u16* __restrict__ xc,
                                             const u16* __restrict__ bmat,
                                             const u16* __restrict__ cmat,
                                             const float* __restrict__ dtp,
                                             const float* __restrict__ alog,
                                             u16* __restrict__ y0, u16* __restrict__ y1) {
  const int h = blockIdx.x & 31;
  const int grp = blockIdx.x >> 5;  // 0..7
  const int dir = grp >> 2;
  const int bt = grp & 3;
  const int tid = threadIdx.x, wave = tid >> 6, lane = tid & 63;
  const float Ah = -expf(alog[h]);

  __shared__ u16 sB[64][72];   // [s][n]
  __shared__ u16 sC[64][72];   // [s][n]
  __shared__ u16 sXM[64][72];  // staged X [s][p]; after transpose reused as M [l][s]
  __shared__ u16 sXT[64][72];  // X^T [p][s]
  __shared__ u16 sBT[64][72];  // B^T [n][s]
  __shared__ float sS[64][68]; // [p][n] running inter-chunk state (f32)
  __shared__ float sAc[64], sEA[64], sSc[64], sDt[64];

  for (int i = tid; i < 64 * 64; i += 256) sS[i >> 6][i & 63] = 0.f;

  const int lr = lane & 15, lg = lane >> 4;
  const int srow = tid >> 2, q = tid & 3;
  const int tp = tid >> 2, ts0 = (tid & 3) << 4;  // transpose mapping

  for (int c = 0; c < NCHUNK; ++c) {
    // ---- P0: stage B, C, X tiles + dt scan ----
    {
      int tdir = c * 64 + srow;
      int rg = bt * LSEQ + (dir ? (LSEQ - 1 - tdir) : tdir);
      const u16* bsrc = bmat + (size_t)rg * 64 + q * 16;
      const u16* csrc = cmat + (size_t)rg * 64 + q * 16;
      const u16* xsrc = xc + (size_t)rg * DINNER + h * 64 + q * 16;
      *(ushort8*)&sB[srow][q * 16] = *(const ushort8*)bsrc;
      *(ushort8*)&sB[srow][q * 16 + 8] = *(const ushort8*)(bsrc + 8);
      *(ushort8*)&sC[srow][q * 16] = *(const ushort8*)csrc;
      *(ushort8*)&sC[srow][q * 16 + 8] = *(const ushort8*)(csrc + 8);
      *(ushort8*)&sXM[srow][q * 16] = *(const ushort8*)xsrc;
      *(ushort8*)&sXM[srow][q * 16 + 8] = *(const ushort8*)(xsrc + 8);
    }
    if (tid < 64) {
      int s = tid;
      float dv = dtp[((size_t)grp * LSEQ + c * 64 + s) * NH + h];
      float a = dv * Ah;
      float x = a;
#pragma unroll
      for (int d = 1; d < 64; d <<= 1) {
        float y = __shfl_up(x, d);
        if (s >= d) x += y;
      }
      float tot = __shfl(x, 63);
      sAc[s] = x;
      sEA[s] = expf(x);
      sSc[s] = expf(tot - x) * dv;  // decay * dt
      sDt[s] = dv;
    }
    __syncthreads();

    // ---- P0b: transpose X and B into row-readable layouts ----
    {
      ushort8 vx0, vx1, vb0, vb1;
#pragma unroll
      for (int i = 0; i < 8; ++i) {
        vx0[i] = sXM[ts0 + i][tp];
        vx1[i] = sXM[ts0 + 8 + i][tp];
        vb0[i] = sB[ts0 + i][tp];
        vb1[i] = sB[ts0 + 8 + i][tp];
      }
      *(ushort8*)&sXT[tp][ts0] = vx0;
      *(ushort8*)&sXT[tp][ts0 + 8] = vx1;
      *(ushort8*)&sBT[tp][ts0] = vb0;
      *(ushort8*)&sBT[tp][ts0 + 8] = vb1;
    }
    __syncthreads();

    // ---- PA: G = C @ B^T -> M (into sXM); Yoff = C @ S_prev^T ----
    f32x4 acc_y[4] = {};
    {
      f32x4 acc_g[4] = {};
#pragma unroll
      for (int ks = 0; ks < 2; ++ks) {
        int kof = ks * 32 + lg * 8;
        short8 af = *(const short8*)&sC[wave * 16 + lr][kof];
#pragma unroll
        for (int nt = 0; nt < 4; ++nt) {
          short8 bf = *(const short8*)&sB[nt * 16 + lr][kof];
          acc_g[nt] = mfma16(af, bf, acc_g[nt]);
        }
      }
#pragma unroll
      for (int ks = 0; ks < 2; ++ks) {
        int kof = ks * 32 + lg * 8;
        short8 af = *(const short8*)&sC[wave * 16 + lr][kof];
#pragma unroll
        for (int nt = 0; nt < 4; ++nt) {
          const float* sr = &sS[nt * 16 + lr][kof];
          f32x4 s0 = *(const f32x4*)sr;
          f32x4 s1 = *(const f32x4*)(sr + 4);
          short8 bf;
#pragma unroll
          for (int e = 0; e < 4; ++e) {
            bf[e] = (short)f2bf(s0[e]);
            bf[e + 4] = (short)f2bf(s1[e]);
          }
          acc_y[nt] = mfma16(af, bf, acc_y[nt]);
        }
      }
      // masked decay matrix M[l][s] -> sXM (sXM's X content is dead: sXT holds it)
#pragma unroll
      for (int nt = 0; nt < 4; ++nt)
#pragma unroll
        for (int rr = 0; rr < 4; ++rr) {
          int l = wave * 16 + lg * 4 + rr;
          int s = nt * 16 + lr;
          float g = acc_g[nt][rr];
          float m = (l >= s) ? g * sDt[s] * expf(sAc[l] - sAc[s]) : 0.f;
          sXM[l][s] = f2bf(m);
        }
    }
    __syncthreads();

    // ---- PB: Y = Yoff*exp(Acum) + M @ X; write Y; S update ----
#pragma unroll
    for (int nt = 0; nt < 4; ++nt)
#pragma unroll
      for (int rr = 0; rr < 4; ++rr) acc_y[nt][rr] *= sEA[wave * 16 + lg * 4 + rr];
#pragma unroll
    for (int ks = 0; ks < 2; ++ks) {
      int kof = ks * 32 + lg * 8;
      short8 af = *(const short8*)&sXM[wave * 16 + lr][kof];
#pragma unroll
      for (int nt = 0; nt < 4; ++nt) {
        short8 bf = *(const short8*)&sXT[nt * 16 + lr][kof];
        acc_y[nt] = mfma16(af, bf, acc_y[nt]);
      }
    }
#pragma unroll
    for (int nt = 0; nt < 4; ++nt)
#pragma unroll
      for (int rr = 0; rr < 4; ++rr) {
        int l = wave * 16 + lg * 4 + rr;
        int p = nt * 16 + lr;
        int tg = c * 64 + l;
        if (tg <= LSEQ - 2) {
          float v = acc_y[nt][rr];
          if (dir == 0)
            y0[((size_t)bt * LSEQ + tg + 1) * DINNER + h * 64 + p] = f2bf(v);
          else
            y1[((size_t)bt * LSEQ + (LSEQ - 2 - tg)) * DINNER + h * 64 + p] = f2bf(v);
        }
      }
    if (c == 0 && tid < 64) {
      if (dir == 0)
        y0[((size_t)bt * LSEQ) * DINNER + h * 64 + tid] = 0;
      else
        y1[((size_t)bt * LSEQ + (LSEQ - 1)) * DINNER + h * 64 + tid] = 0;
    }
    // chunk state: S_new = exp(Asum)*S + (X*decay*dt)^T @ B
    {
      f32x4 acc_s[4] = {};
#pragma unroll
      for (int ks = 0; ks < 2; ++ks) {
        int kof = ks * 32 + lg * 8;
        ushort8 xr = *(const ushort8*)&sXT[wave * 16 + lr][kof];
        short8 af;
#pragma unroll
        for (int e = 0; e < 8; ++e) af[e] = (short)f2bf(bf2f(xr[e]) * sSc[kof + e]);
#pragma unroll
        for (int nt = 0; nt < 4; ++nt) {
          short8 bf = *(const short8*)&sBT[nt * 16 + lr][kof];
          acc_s[nt] = mfma16(af, bf, acc_s[nt]);
        }
      }
      float lam = sEA[63];
#pragma unroll
      for (int nt = 0; nt < 4; ++nt)
#pragma unroll
        for (int rr = 0; rr < 4; ++rr) {
          int p = wave * 16 + lg * 4 + rr;
          int n = nt * 16 + lr;
          sS[p][n] = lam * sS[p][n] + acc_s[nt][rr];
        }
    }
    __syncthreads();
  }
}

// ---------------- Deff = x @ fc_D_w^T + D (LDS-staged, 16 rows/block) ----------------
__global__ __launch_bounds__(256) void k_deff(const u16* __restrict__ xcv,
                                              const float* __restrict__ fw,
                                              const float* __restrict__ Dv,
                                              float* __restrict__ deff) {
  __shared__ u16 sx[16][2064];  // +16 pad: rows land on distinct bank groups
  const int rb = blockIdx.x * 16;
  for (int v = threadIdx.x; v < 4096; v += 256) {
    int r = v >> 8, c = (v & 255) * 8;
    *(ushort8*)&sx[r][c] = *(const ushort8*)(xcv + (size_t)(rb + r) * DINNER + c);
  }
  __syncthreads();
  const int r = threadIdx.x >> 4;
  const int hp = (threadIdx.x & 15) * 2;
  const float* f0 = fw + (size_t)hp * DINNER;
  const float* f1 = f0 + DINNER;
  float a0 = 0.f, a1 = 0.f;
  for (int k = 0; k < DINNER; k += 8) {
    ushort8 xv = *(const ushort8*)&sx[r][k];
    float4 p0 = *(const float4*)(f0 + k);
    float4 p1 = *(const float4*)(f0 + k + 4);
    float4 q0 = *(const float4*)(f1 + k);
    float4 q1 = *(const float4*)(f1 + k + 4);
    a0 += bf2f(xv[0]) * p0.x + bf2f(xv[1]) * p0.y + bf2f(xv[2]) * p0.z + bf2f(xv[3]) * p0.w +
          bf2f(xv[4]) * p1.x + bf2f(xv[5]) * p1.y + bf2f(xv[6]) * p1.z + bf2f(xv[7]) * p1.w;
    a1 += bf2f(xv[0]) * q0.x + bf2f(xv[1]) * q0.y + bf2f(xv[2]) * q0.z + bf2f(xv[3]) * q0.w +
          bf2f(xv[4]) * q1.x + bf2f(xv[5]) * q1.y + bf2f(xv[6]) * q1.z + bf2f(xv[7]) * q1.w;
  }
  deff[(size_t)(rb + r) * NH + hp] = a0 + Dv[hp];
  deff[(size_t)(rb + r) * NH + hp + 1] = a1 + Dv[hp + 1];
}

// ---------------- gating: yn = rmsnorm((y0 + y1 + x*Deff) * silu(z)) * gnw ----------------
__global__ __launch_bounds__(256) void k_gate(const u16* __restrict__ yb0,
                                              const u16* __restrict__ yb1,
                                              const u16* __restrict__ xcv,
                                              const float* __restrict__ deff,
                                              const u16* __restrict__ zb,
                                              const float* __restrict__ gnw,
                                              u16* __restrict__ yn) {
  int row = blockIdx.x, t = threadIdx.x;
  size_t base = (size_t)row * DINNER + t * 8;
  ushort8 y0v = *(const ushort8*)(yb0 + base);
  ushort8 y1v = *(const ushort8*)(yb1 + base);
  ushort8 xv = *(const ushort8*)(xcv + base);
  ushort8 zv = *(const ushort8*)(zb + base);
  float de = deff[row * NH + (t >> 3)];
  float g[8];
  float ss = 0.f;
#pragma unroll
  for (int j = 0; j < 8; ++j) {
    float y = bf2f(y0v[j]) + bf2f(y1v[j]) + bf2f(xv[j]) * de;
    float z = bf2f(zv[j]);
    float gg = y * (z / (1.f + expf(-z)));
    g[j] = gg;
    ss += gg * gg;
  }
  for (int m = 32; m; m >>= 1) ss += __shfl_xor(ss, m);
  __shared__ float wsum[4];
  if ((t & 63) == 0) wsum[t >> 6] = ss;
  __syncthreads();
  float tot = wsum[0] + wsum[1] + wsum[2] + wsum[3];
  float rinv = rsqrtf(tot * (1.0f / DINNER) + 1e-5f);
  u32 w0 = (u32)f2bf(g[0] * rinv * gnw[t * 8 + 0]) | ((u32)f2bf(g[1] * rinv * gnw[t * 8 + 1]) << 16);
  u32 w1 = (u32)f2bf(g[2] * rinv * gnw[t * 8 + 2]) | ((u32)f2bf(g[3] * rinv * gnw[t * 8 + 3]) << 16);
  u32 w2 = (u32)f2bf(g[4] * rinv * gnw[t * 8 + 4]) | ((u32)f2bf(g[5] * rinv * gnw[t * 8 + 5]) << 16);
  u32 w3 = (u32)f2bf(g[6] * rinv * gnw[t * 8 + 6]) | ((u32)f2bf(g[7] * rinv * gnw[t * 8 + 7]) << 16);
  *(uint4*)(yn + base) = make_uint4(w0, w1, w2, w3);
}

extern "C" void kernel_launch(void* const* d_in, const int* in_sizes, int n_in,
                              void* d_out, int out_size, void* d_ws, size_t ws_size,
                              hipStream_t stream) {
  (void)in_sizes; (void)n_in; (void)out_size; (void)ws_size;
  const float* hid = (const float*)d_in[0];
  const float* resin = (const float*)d_in[1];
  const float* nw = (const float*)d_in[2];
  const float* w1 = (const float*)d_in[3];
  const float* cw = (const float*)d_in[4];
  const float* cb = (const float*)d_in[5];
  const float* dtb = (const float*)d_in[6];
  const float* alog = (const float*)d_in[7];
  const float* Dv = (const float*)d_in[8];
  const float* fcw = (const float*)d_in[9];
  const float* gnw = (const float*)d_in[10];
  const float* w2 = (const float*)d_in[11];
  float* out = (float*)d_out;
  float* resout = out + (size_t)ROWS * DMODEL;

  char* ws = (char*)d_ws;
  size_t o = 0;
  auto alloc = [&](size_t bytes) {
    char* p = ws + o;
    o += (bytes + 255) & ~(size_t)255;
    return p;
  };
  u16* W1b = (u16*)alloc((size_t)DIP_PAD * DMODEL * 2);  // 8.9 MB (reused for W2b)
  u16* HN = (u16*)alloc((size_t)ROWS * DMODEL * 2);      // 16.8 MB (reused for YN)
  u16* XBC = (u16*)alloc((size_t)ROWS * CONVD * 2);      // 35.7 MB (reused for YB0)
  u16* ZB = (u16*)alloc((size_t)ROWS * DINNER * 2);      // 33.6 MB
  u16* XC = (u16*)alloc((size_t)ROWS * DINNER * 2);      // 33.6 MB
  u16* BM = (u16*)alloc((size_t)ROWS * 64 * 2);          // 1 MB
  u16* CM = (u16*)alloc((size_t)ROWS * 64 * 2);          // 1 MB
  float* DT = (float*)alloc((size_t)8 * LSEQ * NH * 4);  // 2 MB
  float* DE = (float*)alloc((size_t)ROWS * NH * 4);      // 1 MB
  u16* YB0 = XBC;
  u16* YB1 = (u16*)out;  // out region (33.55 MB) is dead until final GEMM
  u16* W2b = W1b;
  u16* YN = HN;

  k_cast<<<(DIP * DMODEL) / 1024, 256, 0, stream>>>(w1, W1b);
  k_addnorm<<<ROWS, 256, 0, stream>>>(hid, resin, nw, resout, HN);
  // in_proj: M=8192 (64 tiles of 128), N=4352 (17 tiles of 256), K=1024
  k_gemm<0><<<64 * 17, 512, 0, stream>>>(HN, W1b, DMODEL, 17, nullptr, ZB, XBC, DT, dtb);
  k_conv<<<(ROWS * 272) / 256, 256, 0, stream>>>(XBC, cw, cb, XC, BM, CM);
  k_ssd<<<256, 256, 0, stream>>>(XC, BM, CM, DT, alog, YB0, YB1);
  k_cast<<<(DMODEL * DINNER) / 1024, 256, 0, stream>>>(w2, W2b);
  k_deff<<<ROWS / 16, 256, 0, stream>>>(XC, fcw, Dv, DE);
  k_gate<<<ROWS, 256, 0, stream>>>(YB0, YB1, XC, DE, ZB, gnw, YN);
  // out_proj: M=8192 (64 tiles), N=1024 (4 tiles of 256), K=2048
  k_gemm<1><<<64 * 4, 512, 0, stream>>>(YN, W2b, DINNER, 4, out, nullptr, nullptr, nullptr,
                                        nullptr);
}

// Round 7
// 533.552 us; speedup vs baseline: 1.5641x; 1.3962x over previous
//
#include <hip/hip_runtime.h>

typedef __attribute__((ext_vector_type(4))) float f32x4;
typedef __attribute__((ext_vector_type(8))) short short8;
typedef __attribute__((ext_vector_type(8))) unsigned short ushort8;
typedef unsigned short u16;
typedef unsigned int u32;

#define DMODEL 1024
#define DINNER 2048
#define NH     32
#define DIP    4288
#define DIP_PAD 4352
#define CONVD  2176
#define LSEQ   2048
#define ROWS   8192
#define NCHUNK 32

static __device__ __forceinline__ float bf2f(u16 u) {
  u32 x = ((u32)u) << 16;
  return __builtin_bit_cast(float, x);
}
static __device__ __forceinline__ u16 f2bf(float f) {
  u32 x = __builtin_bit_cast(u32, f);
  x += 0x7fffu + ((x >> 16) & 1u);
  return (u16)(x >> 16);
}
static __device__ __forceinline__ f32x4 mfma16(short8 a, short8 b, f32x4 c) {
  return __builtin_amdgcn_mfma_f32_16x16x32_bf16(a, b, c, 0, 0, 0);
}

#define GLDS(gp, lp)                                                     \
  __builtin_amdgcn_global_load_lds(                                     \
      (const __attribute__((address_space(1))) void*)(gp),              \
      (__attribute__((address_space(3))) void*)(lp), 16, 0, 0)

// ---------------- f32 -> bf16 weight cast ----------------
__global__ __launch_bounds__(256) void k_cast(const float* __restrict__ s, u16* __restrict__ d) {
  size_t i = ((size_t)blockIdx.x * 256 + threadIdx.x) * 4;
  float4 v = *(const float4*)(s + i);
  u32 lo = (u32)f2bf(v.x) | ((u32)f2bf(v.y) << 16);
  u32 hi = (u32)f2bf(v.z) | ((u32)f2bf(v.w) << 16);
  *(uint2*)(d + i) = make_uint2(lo, hi);
}

// ---------------- res = h + r ; hnorm = rmsnorm(res)*w (bf16) ----------------
__global__ __launch_bounds__(256) void k_addnorm(const float* __restrict__ h,
                                                 const float* __restrict__ r,
                                                 const float* __restrict__ nw,
                                                 float* __restrict__ res,
                                                 u16* __restrict__ hn) {
  int row = blockIdx.x, t = threadIdx.x;
  const float4* hp = (const float4*)(h + (size_t)row * DMODEL);
  const float4* rp = (const float4*)(r + (size_t)row * DMODEL);
  float4 a = hp[t], b = rp[t];
  float4 s;
  s.x = a.x + b.x; s.y = a.y + b.y; s.z = a.z + b.z; s.w = a.w + b.w;
  ((float4*)(res + (size_t)row * DMODEL))[t] = s;
  float ss = s.x * s.x + s.y * s.y + s.z * s.z + s.w * s.w;
  for (int m = 32; m; m >>= 1) ss += __shfl_xor(ss, m);
  __shared__ float wsum[4];
  if ((t & 63) == 0) wsum[t >> 6] = ss;
  __syncthreads();
  float tot = wsum[0] + wsum[1] + wsum[2] + wsum[3];
  float rinv = rsqrtf(tot * (1.0f / DMODEL) + 1e-5f);
  float4 w4 = ((const float4*)nw)[t];
  u32 lo = (u32)f2bf(s.x * rinv * w4.x) | ((u32)f2bf(s.y * rinv * w4.y) << 16);
  u32 hi = (u32)f2bf(s.z * rinv * w4.z) | ((u32)f2bf(s.w * rinv * w4.w) << 16);
  *(uint2*)(hn + (size_t)row * DMODEL + t * 4) = make_uint2(lo, hi);
}

// ---------------- bf16 MFMA GEMM: 128x256 tile, 8 waves, BK=64, 2-phase 1-barrier ----------------
template <int MODE>
__global__ __launch_bounds__(512) void k_gemm(const u16* __restrict__ A,
                                              const u16* __restrict__ Bw, int K, int nN,
                                              float* __restrict__ outf,
                                              u16* __restrict__ zb, u16* __restrict__ xb,
                                              float* __restrict__ dtp,
                                              const float* __restrict__ dt_bias) {
  constexpr int ABY = 128 * 64 * 2;   // 16 KB A tile
  constexpr int BBY = 256 * 64 * 2;   // 32 KB B tile
  constexpr int TB = ABY + BBY;       // 48 KB per buffer
  __shared__ char lds[2 * TB];

  const int tid = threadIdx.x, wave = tid >> 6, lane = tid & 63;
  const int wm = wave >> 2, wn = wave & 3;
  const int lr = lane & 15, lg = lane >> 4;

  const int cpx = gridDim.x >> 3;
  const int orig = blockIdx.x;
  const int wg = (orig & 7) * cpx + (orig >> 3);
  const int brow = (wg / nN) * 128;
  const int bcol = (wg % nN) * 256;
  const int NK = K >> 6;

  size_t srcA[2], srcB[4];
#pragma unroll
  for (int g = 0; g < 2; ++g) {
    int d = g * 8192 + tid * 16;
    int s = d ^ (((d >> 7) & 7) << 4);
    srcA[g] = (size_t)(brow + (s >> 7)) * K + ((s & 127) >> 1);
  }
#pragma unroll
  for (int g = 0; g < 4; ++g) {
    int d = g * 8192 + tid * 16;
    int s = d ^ (((d >> 7) & 7) << 4);
    srcB[g] = (size_t)(bcol + (s >> 7)) * K + ((s & 127) >> 1);
  }

  auto STAGE = [&](int buf, int kt) {
    char* base = lds + buf * TB;
    size_t koff = (size_t)kt * 64;
#pragma unroll
    for (int g = 0; g < 2; ++g)
      GLDS(A + srcA[g] + koff, base + g * 8192 + wave * 1024);
#pragma unroll
    for (int g = 0; g < 4; ++g)
      GLDS(Bw + srcB[g] + koff, base + ABY + g * 8192 + wave * 1024);
  };

  int offA[4][2], offB[4][2];
#pragma unroll
  for (int i = 0; i < 4; ++i)
#pragma unroll
    for (int ks = 0; ks < 2; ++ks) {
      int rA = wm * 64 + i * 16 + lr;
      offA[i][ks] = (rA * 128 + ks * 64 + lg * 16) ^ ((lr & 7) << 4);
      int rB = wn * 64 + i * 16 + lr;
      offB[i][ks] = ABY + ((rB * 128 + ks * 64 + lg * 16) ^ ((lr & 7) << 4));
    }

  f32x4 acc[4][4] = {};
  STAGE(0, 0);
  asm volatile("s_waitcnt vmcnt(0)" ::: "memory");
  __builtin_amdgcn_s_barrier();
  for (int t = 0; t < NK; ++t) {
    const int cur = t & 1;
    if (t + 1 < NK) STAGE(cur ^ 1, t + 1);
    const char* bb = lds + cur * TB;
    short8 af[4], bfr[4];
#pragma unroll
    for (int i = 0; i < 4; ++i) af[i] = *(const short8*)(bb + offA[i][0]);
#pragma unroll
    for (int j = 0; j < 4; ++j) bfr[j] = *(const short8*)(bb + offB[j][0]);
    __builtin_amdgcn_s_setprio(1);
#pragma unroll
    for (int i = 0; i < 4; ++i)
#pragma unroll
      for (int j = 0; j < 4; ++j) acc[i][j] = mfma16(af[i], bfr[j], acc[i][j]);
    __builtin_amdgcn_s_setprio(0);
#pragma unroll
    for (int i = 0; i < 4; ++i) af[i] = *(const short8*)(bb + offA[i][1]);
#pragma unroll
    for (int j = 0; j < 4; ++j) bfr[j] = *(const short8*)(bb + offB[j][1]);
    __builtin_amdgcn_s_setprio(1);
#pragma unroll
    for (int i = 0; i < 4; ++i)
#pragma unroll
      for (int j = 0; j < 4; ++j) acc[i][j] = mfma16(af[i], bfr[j], acc[i][j]);
    __builtin_amdgcn_s_setprio(0);
    if (t + 1 < NK) {
      asm volatile("s_waitcnt vmcnt(0)" ::: "memory");
      __builtin_amdgcn_s_barrier();
    }
  }

  const int mb = brow + wm * 64 + lg * 4;
  const int nb = bcol + wn * 64 + lr;
#pragma unroll
  for (int i = 0; i < 4; ++i)
#pragma unroll
    for (int j = 0; j < 4; ++j)
#pragma unroll
      for (int rr = 0; rr < 4; ++rr) {
        int m = mb + i * 16 + rr;
        int n = nb + j * 16;
        float v = acc[i][j][rr];
        if constexpr (MODE == 1) {
          outf[(size_t)m * 1024 + n] = v;
        } else {
          if (n < DINNER) {
            zb[(size_t)m * DINNER + n] = f2bf(v);
          } else if (n < DINNER + CONVD) {
            xb[(size_t)m * CONVD + (n - DINNER)] = f2bf(v);
          } else if (n < DIP) {
            int h2 = n - (DINNER + CONVD);  // 0..63
            float uu = v + dt_bias[h2 & 31];
            float sp = (uu > 20.f) ? uu : log1pf(expf(uu));
            int bb2 = m >> 11, tt = m & 2047;
            int obb = bb2, ot = tt;
            if (h2 >= 32) { obb = bb2 + 4; ot = 2047 - tt; }
            dtp[((size_t)(obb << 11) + ot) * NH + (h2 & 31)] = sp;
          }
        }
      }
}

// ---------------- depthwise causal conv (k=4) + SiLU, 8 chans/thread ----------------
__global__ __launch_bounds__(256) void k_conv(const u16* __restrict__ xbc,
                                              const float* __restrict__ cw,
                                              const float* __restrict__ cb,
                                              u16* __restrict__ xc, u16* __restrict__ bm,
                                              u16* __restrict__ cm) {
  int e = blockIdx.x * 256 + threadIdx.x;  // e < ROWS*272
  int c8 = e % 272;
  int r = e / 272;
  int c = c8 * 8;
  int b = r >> 11, t = r & 2047;
  float4 w[8];
  float a[8];
#pragma unroll
  for (int j = 0; j < 8; ++j) {
    w[j] = *(const float4*)&cw[(c + j) * 4];
    a[j] = cb[c + j];
  }
  const u16* base = xbc + (size_t)(b << 11) * CONVD + c;
#pragma unroll
  for (int k = 0; k < 4; ++k) {
    int tt = t - 3 + k;
    if (tt >= 0) {
      ushort8 v = *(const ushort8*)(base + (size_t)tt * CONVD);
#pragma unroll
      for (int j = 0; j < 8; ++j) a[j] += bf2f(v[j]) * ((const float*)&w[j])[k];
    }
  }
  ushort8 o;
#pragma unroll
  for (int j = 0; j < 8; ++j) {
    float s = a[j] * (1.f / (1.f + expf(-a[j])));
    o[j] = f2bf(s);
  }
  if (c8 < 256) *(ushort8*)(xc + (size_t)r * DINNER + c) = o;
  else if (c8 < 264) *(ushort8*)(bm + (size_t)r * 64 + (c - DINNER)) = o;
  else *(ushort8*)(cm + (size_t)r * 64 + (c - DINNER - 64)) = o;
}

// ---------------- fused SSD scan: one block per (dir, batch, head) ----------------
__global__ __launch_bounds__(256) void k_ssd(const u16* __restrict__ xc,
                                             const u16* __restrict__ bmat,
                                             const u16* __restrict__ cmat,
                                             const float* __restrict__ dtp,
                                             const float* __restrict__ alog,
                                             u16* __restrict__ y0, u16* __restrict__ y1) {
  const int h = blockIdx.x & 31;
  const int grp = blockIdx.x >> 5;  // 0..7
  const int dir = grp >> 2;
  const int bt = grp & 3;
  const int tid = threadIdx.x, wave = tid >> 6, lane = tid & 63;
  const float Ah = -expf(alog[h]);

  __shared__ u16 sB[64][72];   // [s][n]
  __shared__ u16 sC[64][72];   // [s][n]
  __shared__ u16 sXM[64][72];  // staged X [s][p]; after transpose reused as M [l][s]
  __shared__ u16 sXT[64][72];  // X^T [p][s]
  __shared__ u16 sBT[64][72];  // B^T [n][s]
  __shared__ float sS[64][68]; // [p][n] running inter-chunk state (f32)
  __shared__ float sAc[64], sEA[64], sSc[64], sDt[64];

  for (int i = tid; i < 64 * 64; i += 256) sS[i >> 6][i & 63] = 0.f;

  const int lr = lane & 15, lg = lane >> 4;
  const int srow = tid >> 2, q = tid & 3;
  const int tp = tid >> 2, ts0 = (tid & 3) << 4;  // transpose mapping

  for (int c = 0; c < NCHUNK; ++c) {
    // ---- P0: stage B, C, X tiles + dt scan ----
    {
      int tdir = c * 64 + srow;
      int rg = bt * LSEQ + (dir ? (LSEQ - 1 - tdir) : tdir);
      const u16* bsrc = bmat + (size_t)rg * 64 + q * 16;
      const u16* csrc = cmat + (size_t)rg * 64 + q * 16;
      const u16* xsrc = xc + (size_t)rg * DINNER + h * 64 + q * 16;
      *(ushort8*)&sB[srow][q * 16] = *(const ushort8*)bsrc;
      *(ushort8*)&sB[srow][q * 16 + 8] = *(const ushort8*)(bsrc + 8);
      *(ushort8*)&sC[srow][q * 16] = *(const ushort8*)csrc;
      *(ushort8*)&sC[srow][q * 16 + 8] = *(const ushort8*)(csrc + 8);
      *(ushort8*)&sXM[srow][q * 16] = *(const ushort8*)xsrc;
      *(ushort8*)&sXM[srow][q * 16 + 8] = *(const ushort8*)(xsrc + 8);
    }
    if (tid < 64) {
      int s = tid;
      float dv = dtp[((size_t)grp * LSEQ + c * 64 + s) * NH + h];
      float a = dv * Ah;
      float x = a;
#pragma unroll
      for (int d = 1; d < 64; d <<= 1) {
        float y = __shfl_up(x, d);
        if (s >= d) x += y;
      }
      float tot = __shfl(x, 63);
      sAc[s] = x;
      sEA[s] = expf(x);
      sSc[s] = expf(tot - x) * dv;  // decay * dt
      sDt[s] = dv;
    }
    __syncthreads();

    // ---- P0b: transpose X and B into row-readable layouts ----
    {
      ushort8 vx0, vx1, vb0, vb1;
#pragma unroll
      for (int i = 0; i < 8; ++i) {
        vx0[i] = sXM[ts0 + i][tp];
        vx1[i] = sXM[ts0 + 8 + i][tp];
        vb0[i] = sB[ts0 + i][tp];
        vb1[i] = sB[ts0 + 8 + i][tp];
      }
      *(ushort8*)&sXT[tp][ts0] = vx0;
      *(ushort8*)&sXT[tp][ts0 + 8] = vx1;
      *(ushort8*)&sBT[tp][ts0] = vb0;
      *(ushort8*)&sBT[tp][ts0 + 8] = vb1;
    }
    __syncthreads();

    // ---- PA: G = C @ B^T -> M (into sXM); Yoff = C @ S_prev^T ----
    f32x4 acc_y[4] = {};
    {
      f32x4 acc_g[4] = {};
#pragma unroll
      for (int ks = 0; ks < 2; ++ks) {
        int kof = ks * 32 + lg * 8;
        short8 af = *(const short8*)&sC[wave * 16 + lr][kof];
#pragma unroll
        for (int nt = 0; nt < 4; ++nt) {
          short8 bf = *(const short8*)&sB[nt * 16 + lr][kof];
          acc_g[nt] = mfma16(af, bf, acc_g[nt]);
        }
      }
#pragma unroll
      for (int ks = 0; ks < 2; ++ks) {
        int kof = ks * 32 + lg * 8;
        short8 af = *(const short8*)&sC[wave * 16 + lr][kof];
#pragma unroll
        for (int nt = 0; nt < 4; ++nt) {
          const float* sr = &sS[nt * 16 + lr][kof];
          f32x4 s0 = *(const f32x4*)sr;
          f32x4 s1 = *(const f32x4*)(sr + 4);
          short8 bf;
#pragma unroll
          for (int e = 0; e < 4; ++e) {
            bf[e] = (short)f2bf(s0[e]);
            bf[e + 4] = (short)f2bf(s1[e]);
          }
          acc_y[nt] = mfma16(af, bf, acc_y[nt]);
        }
      }
      // masked decay matrix M[l][s] -> sXM (sXM's X content is dead: sXT holds it)
#pragma unroll
      for (int nt = 0; nt < 4; ++nt)
#pragma unroll
        for (int rr = 0; rr < 4; ++rr) {
          int l = wave * 16 + lg * 4 + rr;
          int s = nt * 16 + lr;
          float g = acc_g[nt][rr];
          float m = (l >= s) ? g * sDt[s] * expf(sAc[l] - sAc[s]) : 0.f;
          sXM[l][s] = f2bf(m);
        }
    }
    __syncthreads();

    // ---- PB: Y = Yoff*exp(Acum) + M @ X; write Y; S update ----
#pragma unroll
    for (int nt = 0; nt < 4; ++nt)
#pragma unroll
      for (int rr = 0; rr < 4; ++rr) acc_y[nt][rr] *= sEA[wave * 16 + lg * 4 + rr];
#pragma unroll
    for (int ks = 0; ks < 2; ++ks) {
      int kof = ks * 32 + lg * 8;
      short8 af = *(const short8*)&sXM[wave * 16 + lr][kof];
#pragma unroll
      for (int nt = 0; nt < 4; ++nt) {
        short8 bf = *(const short8*)&sXT[nt * 16 + lr][kof];
        acc_y[nt] = mfma16(af, bf, acc_y[nt]);
      }
    }
#pragma unroll
    for (int nt = 0; nt < 4; ++nt)
#pragma unroll
      for (int rr = 0; rr < 4; ++rr) {
        int l = wave * 16 + lg * 4 + rr;
        int p = nt * 16 + lr;
        int tg = c * 64 + l;
        if (tg <= LSEQ - 2) {
          float v = acc_y[nt][rr];
          if (dir == 0)
            y0[((size_t)bt * LSEQ + tg + 1) * DINNER + h * 64 + p] = f2bf(v);
          else
            y1[((size_t)bt * LSEQ + (LSEQ - 2 - tg)) * DINNER + h * 64 + p] = f2bf(v);
        }
      }
    if (c == 0 && tid < 64) {
      if (dir == 0)
        y0[((size_t)bt * LSEQ) * DINNER + h * 64 + tid] = 0;
      else
        y1[((size_t)bt * LSEQ + (LSEQ - 1)) * DINNER + h * 64 + tid] = 0;
    }
    // chunk state: S_new = exp(Asum)*S + (X*decay*dt)^T @ B
    {
      f32x4 acc_s[4] = {};
#pragma unroll
      for (int ks = 0; ks < 2; ++ks) {
        int kof = ks * 32 + lg * 8;
        ushort8 xr = *(const ushort8*)&sXT[wave * 16 + lr][kof];
        short8 af;
#pragma unroll
        for (int e = 0; e < 8; ++e) af[e] = (short)f2bf(bf2f(xr[e]) * sSc[kof + e]);
#pragma unroll
        for (int nt = 0; nt < 4; ++nt) {
          short8 bf = *(const short8*)&sBT[nt * 16 + lr][kof];
          acc_s[nt] = mfma16(af, bf, acc_s[nt]);
        }
      }
      float lam = sEA[63];
#pragma unroll
      for (int nt = 0; nt < 4; ++nt)
#pragma unroll
        for (int rr = 0; rr < 4; ++rr) {
          int p = wave * 16 + lg * 4 + rr;
          int n = nt * 16 + lr;
          sS[p][n] = lam * sS[p][n] + acc_s[nt][rr];
        }
    }
    __syncthreads();
  }
}

// ---------------- Deff = x @ fc_D_w^T + D  (MFMA, split-K, 32 rows/block) ----------------
// Wave layout: A = fwb (bf16 fc_D_w), 16 heads/frag; B = 16 x-rows direct from global.
// waves 0,1: rows {0-15},{16-31} with K in [0,1024); waves 2,3: same rows, K in [1024,2048).
// D frag: head = lg*4+rr, row = lr (verified layout from working GEMM). LDS-reduce halves.
__global__ __launch_bounds__(256) void k_deff(const u16* __restrict__ xcv,
                                              const u16* __restrict__ fwb,
                                              const float* __restrict__ Dv,
                                              float* __restrict__ deff) {
  __shared__ float red[2][64][8];
  const int tid = threadIdx.x, wave = tid >> 6, lane = tid & 63;
  const int lr = lane & 15, lg = lane >> 4;
  const int rowg = wave & 1;
  const int kg = wave >> 1;
  const int rb = blockIdx.x * 32 + rowg * 16;
  const u16* xrow = xcv + (size_t)(rb + lr) * DINNER + kg * 1024 + lg * 8;
  const u16* f0 = fwb + (size_t)lr * DINNER + kg * 1024 + lg * 8;
  const u16* f1 = fwb + (size_t)(16 + lr) * DINNER + kg * 1024 + lg * 8;
  f32x4 a0 = {}, a1 = {};
  for (int k = 0; k < 1024; k += 32) {
    short8 bf = *(const short8*)(xrow + k);
    short8 af0 = *(const short8*)(f0 + k);
    short8 af1 = *(const short8*)(f1 + k);
    a0 = mfma16(af0, bf, a0);
    a1 = mfma16(af1, bf, a1);
  }
  if (kg == 1) {
#pragma unroll
    for (int rr = 0; rr < 4; ++rr) {
      red[rowg][lane][rr] = a0[rr];
      red[rowg][lane][4 + rr] = a1[rr];
    }
  }
  __syncthreads();
  if (kg == 0) {
    float4 o0, o1;
#pragma unroll
    for (int rr = 0; rr < 4; ++rr) {
      ((float*)&o0)[rr] = a0[rr] + red[rowg][lane][rr] + Dv[lg * 4 + rr];
      ((float*)&o1)[rr] = a1[rr] + red[rowg][lane][4 + rr] + Dv[16 + lg * 4 + rr];
    }
    *(float4*)&deff[(size_t)(rb + lr) * NH + lg * 4] = o0;
    *(float4*)&deff[(size_t)(rb + lr) * NH + 16 + lg * 4] = o1;
  }
}

// ---------------- gating: yn = rmsnorm((y0 + y1 + x*Deff) * silu(z)) * gnw ----------------
__global__ __launch_bounds__(256) void k_gate(const u16* __restrict__ yb0,
                                              const u16* __restrict__ yb1,
                                              const u16* __restrict__ xcv,
                                              const float* __restrict__ deff,
                                              const u16* __restrict__ zb,
                                              const float* __restrict__ gnw,
                                              u16* __restrict__ yn) {
  int row = blockIdx.x, t = threadIdx.x;
  size_t base = (size_t)row * DINNER + t * 8;
  ushort8 y0v = *(const ushort8*)(yb0 + base);
  ushort8 y1v = *(const ushort8*)(yb1 + base);
  ushort8 xv = *(const ushort8*)(xcv + base);
  ushort8 zv = *(const ushort8*)(zb + base);
  float de = deff[row * NH + (t >> 3)];
  float g[8];
  float ss = 0.f;
#pragma unroll
  for (int j = 0; j < 8; ++j) {
    float y = bf2f(y0v[j]) + bf2f(y1v[j]) + bf2f(xv[j]) * de;
    float z = bf2f(zv[j]);
    float gg = y * (z / (1.f + expf(-z)));
    g[j] = gg;
    ss += gg * gg;
  }
  for (int m = 32; m; m >>= 1) ss += __shfl_xor(ss, m);
  __shared__ float wsum[4];
  if ((t & 63) == 0) wsum[t >> 6] = ss;
  __syncthreads();
  float tot = wsum[0] + wsum[1] + wsum[2] + wsum[3];
  float rinv = rsqrtf(tot * (1.0f / DINNER) + 1e-5f);
  u32 w0 = (u32)f2bf(g[0] * rinv * gnw[t * 8 + 0]) | ((u32)f2bf(g[1] * rinv * gnw[t * 8 + 1]) << 16);
  u32 w1 = (u32)f2bf(g[2] * rinv * gnw[t * 8 + 2]) | ((u32)f2bf(g[3] * rinv * gnw[t * 8 + 3]) << 16);
  u32 w2 = (u32)f2bf(g[4] * rinv * gnw[t * 8 + 4]) | ((u32)f2bf(g[5] * rinv * gnw[t * 8 + 5]) << 16);
  u32 w3 = (u32)f2bf(g[6] * rinv * gnw[t * 8 + 6]) | ((u32)f2bf(g[7] * rinv * gnw[t * 8 + 7]) << 16);
  *(uint4*)(yn + base) = make_uint4(w0, w1, w2, w3);
}

extern "C" void kernel_launch(void* const* d_in, const int* in_sizes, int n_in,
                              void* d_out, int out_size, void* d_ws, size_t ws_size,
                              hipStream_t stream) {
  (void)in_sizes; (void)n_in; (void)out_size; (void)ws_size;
  const float* hid = (const float*)d_in[0];
  const float* resin = (const float*)d_in[1];
  const float* nw = (const float*)d_in[2];
  const float* w1 = (const float*)d_in[3];
  const float* cw = (const float*)d_in[4];
  const float* cb = (const float*)d_in[5];
  const float* dtb = (const float*)d_in[6];
  const float* alog = (const float*)d_in[7];
  const float* Dv = (const float*)d_in[8];
  const float* fcw = (const float*)d_in[9];
  const float* gnw = (const float*)d_in[10];
  const float* w2 = (const float*)d_in[11];
  float* out = (float*)d_out;
  float* resout = out + (size_t)ROWS * DMODEL;

  char* ws = (char*)d_ws;
  size_t o = 0;
  auto alloc = [&](size_t bytes) {
    char* p = ws + o;
    o += (bytes + 255) & ~(size_t)255;
    return p;
  };
  u16* W1b = (u16*)alloc((size_t)DIP_PAD * DMODEL * 2);  // 8.9 MB (reused for W2b)
  u16* HN = (u16*)alloc((size_t)ROWS * DMODEL * 2);      // 16.8 MB (reused for YN)
  u16* XBC = (u16*)alloc((size_t)ROWS * CONVD * 2);      // 35.7 MB (reused for YB0)
  u16* ZB = (u16*)alloc((size_t)ROWS * DINNER * 2);      // 33.6 MB
  u16* XC = (u16*)alloc((size_t)ROWS * DINNER * 2);      // 33.6 MB
  u16* BM = (u16*)alloc((size_t)ROWS * 64 * 2);          // 1 MB
  u16* CM = (u16*)alloc((size_t)ROWS * 64 * 2);          // 1 MB
  float* DT = (float*)alloc((size_t)8 * LSEQ * NH * 4);  // 2 MB
  float* DE = (float*)alloc((size_t)ROWS * NH * 4);      // 1 MB
  u16* FWB = (u16*)alloc((size_t)NH * DINNER * 2);       // 128 KB
  u16* YB0 = XBC;
  u16* YB1 = (u16*)out;  // out region (33.55 MB) is dead until final GEMM
  u16* W2b = W1b;
  u16* YN = HN;

  k_cast<<<(DIP * DMODEL) / 1024, 256, 0, stream>>>(w1, W1b);
  k_addnorm<<<ROWS, 256, 0, stream>>>(hid, resin, nw, resout, HN);
  // in_proj: M=8192 (64 tiles of 128), N=4352 (17 tiles of 256), K=1024
  k_gemm<0><<<64 * 17, 512, 0, stream>>>(HN, W1b, DMODEL, 17, nullptr, ZB, XBC, DT, dtb);
  k_conv<<<(ROWS * 272) / 256, 256, 0, stream>>>(XBC, cw, cb, XC, BM, CM);
  k_ssd<<<256, 256, 0, stream>>>(XC, BM, CM, DT, alog, YB0, YB1);
  k_cast<<<(DMODEL * DINNER) / 1024, 256, 0, stream>>>(w2, W2b);
  k_cast<<<(NH * DINNER) / 1024, 256, 0, stream>>>(fcw, FWB);
  k_deff<<<ROWS / 32, 256, 0, stream>>>(XC, FWB, Dv, DE);
  k_gate<<<ROWS, 256, 0, stream>>>(YB0, YB1, XC, DE, ZB, gnw, YN);
  // out_proj: M=8192 (64 tiles), N=1024 (4 tiles of 256), K=2048
  k_gemm<1><<<64 * 4, 512, 0, stream>>>(YN, W2b, DINNER, 4, out, nullptr, nullptr, nullptr,
                                        nullptr);
}

// Round 8
// 448.373 us; speedup vs baseline: 1.8613x; 1.1900x over previous
//
#include <hip/hip_runtime.h>

typedef __attribute__((ext_vector_type(4))) float f32x4;
typedef __attribute__((ext_vector_type(8))) short short8;
typedef __attribute__((ext_vector_type(8))) unsigned short ushort8;
typedef unsigned short u16;
typedef unsigned int u32;

#define DMODEL 1024
#define DINNER 2048
#define NH     32
#define DIP    4288
#define DIP_PAD 4352
#define CONVD  2176
#define LSEQ   2048
#define ROWS   8192
#define NCHUNK 32

static __device__ __forceinline__ float bf2f(u16 u) {
  u32 x = ((u32)u) << 16;
  return __builtin_bit_cast(float, x);
}
static __device__ __forceinline__ u16 f2bf(float f) {
  u32 x = __builtin_bit_cast(u32, f);
  x += 0x7fffu + ((x >> 16) & 1u);
  return (u16)(x >> 16);
}
static __device__ __forceinline__ f32x4 mfma16(short8 a, short8 b, f32x4 c) {
  return __builtin_amdgcn_mfma_f32_16x16x32_bf16(a, b, c, 0, 0, 0);
}

#define GLDS(gp, lp)                                                     \
  __builtin_amdgcn_global_load_lds(                                     \
      (const __attribute__((address_space(1))) void*)(gp),              \
      (__attribute__((address_space(3))) void*)(lp), 16, 0, 0)

// ---------------- f32 -> bf16 weight cast ----------------
__global__ __launch_bounds__(256) void k_cast(const float* __restrict__ s, u16* __restrict__ d) {
  size_t i = ((size_t)blockIdx.x * 256 + threadIdx.x) * 4;
  float4 v = *(const float4*)(s + i);
  u32 lo = (u32)f2bf(v.x) | ((u32)f2bf(v.y) << 16);
  u32 hi = (u32)f2bf(v.z) | ((u32)f2bf(v.w) << 16);
  *(uint2*)(d + i) = make_uint2(lo, hi);
}

// ---------------- res = h + r ; hnorm = rmsnorm(res)*w (bf16) ----------------
__global__ __launch_bounds__(256) void k_addnorm(const float* __restrict__ h,
                                                 const float* __restrict__ r,
                                                 const float* __restrict__ nw,
                                                 float* __restrict__ res,
                                                 u16* __restrict__ hn) {
  int row = blockIdx.x, t = threadIdx.x;
  const float4* hp = (const float4*)(h + (size_t)row * DMODEL);
  const float4* rp = (const float4*)(r + (size_t)row * DMODEL);
  float4 a = hp[t], b = rp[t];
  float4 s;
  s.x = a.x + b.x; s.y = a.y + b.y; s.z = a.z + b.z; s.w = a.w + b.w;
  ((float4*)(res + (size_t)row * DMODEL))[t] = s;
  float ss = s.x * s.x + s.y * s.y + s.z * s.z + s.w * s.w;
  for (int m = 32; m; m >>= 1) ss += __shfl_xor(ss, m);
  __shared__ float wsum[4];
  if ((t & 63) == 0) wsum[t >> 6] = ss;
  __syncthreads();
  float tot = wsum[0] + wsum[1] + wsum[2] + wsum[3];
  float rinv = rsqrtf(tot * (1.0f / DMODEL) + 1e-5f);
  float4 w4 = ((const float4*)nw)[t];
  u32 lo = (u32)f2bf(s.x * rinv * w4.x) | ((u32)f2bf(s.y * rinv * w4.y) << 16);
  u32 hi = (u32)f2bf(s.z * rinv * w4.z) | ((u32)f2bf(s.w * rinv * w4.w) << 16);
  *(uint2*)(hn + (size_t)row * DMODEL + t * 4) = make_uint2(lo, hi);
}

// ---------------- bf16 MFMA GEMM: 128x256 tile, 8 waves, BK=64, 2-phase 1-barrier ----------------
template <int MODE>
__global__ __launch_bounds__(512) void k_gemm(const u16* __restrict__ A,
                                              const u16* __restrict__ Bw, int K, int nN,
                                              float* __restrict__ outf,
                                              u16* __restrict__ zb, u16* __restrict__ xb,
                                              float* __restrict__ dtp,
                                              const float* __restrict__ dt_bias) {
  constexpr int ABY = 128 * 64 * 2;   // 16 KB A tile
  constexpr int BBY = 256 * 64 * 2;   // 32 KB B tile
  constexpr int TB = ABY + BBY;       // 48 KB per buffer
  __shared__ char lds[2 * TB];

  const int tid = threadIdx.x, wave = tid >> 6, lane = tid & 63;
  const int wm = wave >> 2, wn = wave & 3;
  const int lr = lane & 15, lg = lane >> 4;

  const int cpx = gridDim.x >> 3;
  const int orig = blockIdx.x;
  const int wg = (orig & 7) * cpx + (orig >> 3);
  const int brow = (wg / nN) * 128;
  const int bcol = (wg % nN) * 256;
  const int NK = K >> 6;

  size_t srcA[2], srcB[4];
#pragma unroll
  for (int g = 0; g < 2; ++g) {
    int d = g * 8192 + tid * 16;
    int s = d ^ (((d >> 7) & 7) << 4);
    srcA[g] = (size_t)(brow + (s >> 7)) * K + ((s & 127) >> 1);
  }
#pragma unroll
  for (int g = 0; g < 4; ++g) {
    int d = g * 8192 + tid * 16;
    int s = d ^ (((d >> 7) & 7) << 4);
    srcB[g] = (size_t)(bcol + (s >> 7)) * K + ((s & 127) >> 1);
  }

  auto STAGE = [&](int buf, int kt) {
    char* base = lds + buf * TB;
    size_t koff = (size_t)kt * 64;
#pragma unroll
    for (int g = 0; g < 2; ++g)
      GLDS(A + srcA[g] + koff, base + g * 8192 + wave * 1024);
#pragma unroll
    for (int g = 0; g < 4; ++g)
      GLDS(Bw + srcB[g] + koff, base + ABY + g * 8192 + wave * 1024);
  };

  int offA[4][2], offB[4][2];
#pragma unroll
  for (int i = 0; i < 4; ++i)
#pragma unroll
    for (int ks = 0; ks < 2; ++ks) {
      int rA = wm * 64 + i * 16 + lr;
      offA[i][ks] = (rA * 128 + ks * 64 + lg * 16) ^ ((lr & 7) << 4);
      int rB = wn * 64 + i * 16 + lr;
      offB[i][ks] = ABY + ((rB * 128 + ks * 64 + lg * 16) ^ ((lr & 7) << 4));
    }

  f32x4 acc[4][4] = {};
  STAGE(0, 0);
  asm volatile("s_waitcnt vmcnt(0)" ::: "memory");
  __builtin_amdgcn_s_barrier();
  for (int t = 0; t < NK; ++t) {
    const int cur = t & 1;
    if (t + 1 < NK) STAGE(cur ^ 1, t + 1);
    const char* bb = lds + cur * TB;
    short8 af[4], bfr[4];
#pragma unroll
    for (int i = 0; i < 4; ++i) af[i] = *(const short8*)(bb + offA[i][0]);
#pragma unroll
    for (int j = 0; j < 4; ++j) bfr[j] = *(const short8*)(bb + offB[j][0]);
    __builtin_amdgcn_s_setprio(1);
#pragma unroll
    for (int i = 0; i < 4; ++i)
#pragma unroll
      for (int j = 0; j < 4; ++j) acc[i][j] = mfma16(af[i], bfr[j], acc[i][j]);
    __builtin_amdgcn_s_setprio(0);
#pragma unroll
    for (int i = 0; i < 4; ++i) af[i] = *(const short8*)(bb + offA[i][1]);
#pragma unroll
    for (int j = 0; j < 4; ++j) bfr[j] = *(const short8*)(bb + offB[j][1]);
    __builtin_amdgcn_s_setprio(1);
#pragma unroll
    for (int i = 0; i < 4; ++i)
#pragma unroll
      for (int j = 0; j < 4; ++j) acc[i][j] = mfma16(af[i], bfr[j], acc[i][j]);
    __builtin_amdgcn_s_setprio(0);
    if (t + 1 < NK) {
      asm volatile("s_waitcnt vmcnt(0)" ::: "memory");
      __builtin_amdgcn_s_barrier();
    }
  }

  const int mb = brow + wm * 64 + lg * 4;
  const int nb = bcol + wn * 64 + lr;
#pragma unroll
  for (int i = 0; i < 4; ++i)
#pragma unroll
    for (int j = 0; j < 4; ++j)
#pragma unroll
      for (int rr = 0; rr < 4; ++rr) {
        int m = mb + i * 16 + rr;
        int n = nb + j * 16;
        float v = acc[i][j][rr];
        if constexpr (MODE == 1) {
          outf[(size_t)m * 1024 + n] = v;
        } else {
          if (n < DINNER) {
            zb[(size_t)m * DINNER + n] = f2bf(v);
          } else if (n < DINNER + CONVD) {
            xb[(size_t)m * CONVD + (n - DINNER)] = f2bf(v);
          } else if (n < DIP) {
            int h2 = n - (DINNER + CONVD);  // 0..63
            float uu = v + dt_bias[h2 & 31];
            float sp = (uu > 20.f) ? uu : log1pf(expf(uu));
            int bb2 = m >> 11, tt = m & 2047;
            int obb = bb2, ot = tt;
            if (h2 >= 32) { obb = bb2 + 4; ot = 2047 - tt; }
            dtp[((size_t)(obb << 11) + ot) * NH + (h2 & 31)] = sp;
          }
        }
      }
}

// ---------------- depthwise causal conv (k=4) + SiLU, 8 chans/thread ----------------
__global__ __launch_bounds__(256) void k_conv(const u16* __restrict__ xbc,
                                              const float* __restrict__ cw,
                                              const float* __restrict__ cb,
                                              u16* __restrict__ xc, u16* __restrict__ bm,
                                              u16* __restrict__ cm) {
  int e = blockIdx.x * 256 + threadIdx.x;  // e < ROWS*272
  int c8 = e % 272;
  int r = e / 272;
  int c = c8 * 8;
  int b = r >> 11, t = r & 2047;
  float4 w[8];
  float a[8];
#pragma unroll
  for (int j = 0; j < 8; ++j) {
    w[j] = *(const float4*)&cw[(c + j) * 4];
    a[j] = cb[c + j];
  }
  const u16* base = xbc + (size_t)(b << 11) * CONVD + c;
#pragma unroll
  for (int k = 0; k < 4; ++k) {
    int tt = t - 3 + k;
    if (tt >= 0) {
      ushort8 v = *(const ushort8*)(base + (size_t)tt * CONVD);
#pragma unroll
      for (int j = 0; j < 8; ++j) a[j] += bf2f(v[j]) * ((const float*)&w[j])[k];
    }
  }
  ushort8 o;
#pragma unroll
  for (int j = 0; j < 8; ++j) {
    float s = a[j] * (1.f / (1.f + expf(-a[j])));
    o[j] = f2bf(s);
  }
  if (c8 < 256) *(ushort8*)(xc + (size_t)r * DINNER + c) = o;
  else if (c8 < 264) *(ushort8*)(bm + (size_t)r * 64 + (c - DINNER)) = o;
  else *(ushort8*)(cm + (size_t)r * 64 + (c - DINNER - 64)) = o;
}

// ---------------- fused SSD scan v2: 8 waves, one block per (dir, batch, head) ----------------
// Per wave: l-quarter lq = wave>>1, n/p-half wh = wave&1 -> 16 MFMA/wave/chunk.
// Transpose via row-read orientation (conflict-free scalar reads); bf16 state
// shadow sSb kills per-chunk f32->bf16 repack; next-chunk loads issued early.
__global__ __launch_bounds__(512) void k_ssd(const u16* __restrict__ xc,
                                             const u16* __restrict__ bmat,
                                             const u16* __restrict__ cmat,
                                             const float* __restrict__ dtp,
                                             const float* __restrict__ alog,
                                             u16* __restrict__ y0, u16* __restrict__ y1) {
  const int h = blockIdx.x & 31;
  const int grp = blockIdx.x >> 5;  // 0..7
  const int dir = grp >> 2;
  const int bt = grp & 3;
  const int tid = threadIdx.x, wave = tid >> 6, lane = tid & 63;
  const int lq = wave >> 1, wh = wave & 1;
  const int lr = lane & 15, lg = lane >> 4;
  const float Ah = -expf(alog[h]);

  __shared__ u16 sB[64][72];    // [s][n]
  __shared__ u16 sC[64][72];    // [s][n]
  __shared__ u16 sXM[64][72];   // staged X [s][p]; reused as M [l][s] after transpose
  __shared__ u16 sXT[64][72];   // X^T [p][s]
  __shared__ u16 sBT[64][72];   // B^T [n][s]
  __shared__ u16 sSb[64][72];   // bf16 shadow of state [p][n]
  __shared__ float sS[64][68];  // f32 state accumulator [p][n]
  __shared__ float sAc[64], sEA[64], sSc[64], sDt[64];

  for (int i = tid; i < 64 * 64; i += 512) {
    sS[i >> 6][i & 63] = 0.f;
    sSb[i >> 6][i & 63] = 0;
  }

  const int srow = tid >> 3, q8 = (tid & 7) * 8;

  auto rowOf = [&](int c) {
    int tdir = c * 64 + srow;
    return bt * LSEQ + (dir ? (LSEQ - 1 - tdir) : tdir);
  };

  int rg = rowOf(0);
  ushort8 rB = *(const ushort8*)(bmat + (size_t)rg * 64 + q8);
  ushort8 rC = *(const ushort8*)(cmat + (size_t)rg * 64 + q8);
  ushort8 rX = *(const ushort8*)(xc + (size_t)rg * DINNER + h * 64 + q8);

  for (int c = 0; c < NCHUNK; ++c) {
    // ---- stage (regs -> LDS) ----
    *(ushort8*)&sB[srow][q8] = rB;
    *(ushort8*)&sC[srow][q8] = rC;
    *(ushort8*)&sXM[srow][q8] = rX;
    __syncthreads();  // bar1

    // ---- transpose X, B (wave reads rows w*8..w*8+7, lane = column) + dt scan ----
    {
      ushort8 vx, vb;
#pragma unroll
      for (int i = 0; i < 8; ++i) {
        vx[i] = sXM[wave * 8 + i][lane];
        vb[i] = sB[wave * 8 + i][lane];
      }
      *(ushort8*)&sXT[lane][wave * 8] = vx;
      *(ushort8*)&sBT[lane][wave * 8] = vb;
    }
    if (wave == 0) {
      int s = lane;
      float dv = dtp[((size_t)grp * LSEQ + c * 64 + s) * NH + h];
      float a = dv * Ah;
      float x = a;
#pragma unroll
      for (int d = 1; d < 64; d <<= 1) {
        float y = __shfl_up(x, d);
        if (s >= d) x += y;
      }
      float tot = __shfl(x, 63);
      sAc[s] = x;
      sEA[s] = expf(x);
      sSc[s] = expf(tot - x) * dv;
      sDt[s] = dv;
    }
    __syncthreads();  // bar2

    // ---- early-issue next chunk's global loads (land during PA/PB) ----
    if (c + 1 < NCHUNK) {
      int rg2 = rowOf(c + 1);
      rB = *(const ushort8*)(bmat + (size_t)rg2 * 64 + q8);
      rC = *(const ushort8*)(cmat + (size_t)rg2 * 64 + q8);
      rX = *(const ushort8*)(xc + (size_t)rg2 * DINNER + h * 64 + q8);
    }

    // ---- PA: G = C@B^T -> M (into sXM); Yoff = C @ sSb^T ----
    f32x4 acc_y[2] = {};
    {
      f32x4 acc_g[2] = {};
#pragma unroll
      for (int ks = 0; ks < 2; ++ks) {
        int kof = ks * 32 + lg * 8;
        short8 af = *(const short8*)&sC[lq * 16 + lr][kof];
#pragma unroll
        for (int nt = 0; nt < 2; ++nt) {
          short8 bf = *(const short8*)&sB[wh * 32 + nt * 16 + lr][kof];
          acc_g[nt] = mfma16(af, bf, acc_g[nt]);
        }
      }
#pragma unroll
      for (int ks = 0; ks < 2; ++ks) {
        int kof = ks * 32 + lg * 8;
        short8 af = *(const short8*)&sC[lq * 16 + lr][kof];
#pragma unroll
        for (int nt = 0; nt < 2; ++nt) {
          short8 bf = *(const short8*)&sSb[wh * 32 + nt * 16 + lr][kof];
          acc_y[nt] = mfma16(af, bf, acc_y[nt]);
        }
      }
#pragma unroll
      for (int nt = 0; nt < 2; ++nt)
#pragma unroll
        for (int rr = 0; rr < 4; ++rr) {
          int l = lq * 16 + lg * 4 + rr;
          int s = wh * 32 + nt * 16 + lr;
          float g = acc_g[nt][rr];
          float m = (l >= s) ? g * sDt[s] * expf(sAc[l] - sAc[s]) : 0.f;
          sXM[l][s] = f2bf(m);
        }
    }
    __syncthreads();  // bar3

    // ---- PB: Y = Yoff*exp(Ac) + M@X^T; store; S update ----
#pragma unroll
    for (int nt = 0; nt < 2; ++nt)
#pragma unroll
      for (int rr = 0; rr < 4; ++rr) acc_y[nt][rr] *= sEA[lq * 16 + lg * 4 + rr];
#pragma unroll
    for (int ks = 0; ks < 2; ++ks) {
      int kof = ks * 32 + lg * 8;
      short8 af = *(const short8*)&sXM[lq * 16 + lr][kof];
#pragma unroll
      for (int nt = 0; nt < 2; ++nt) {
        short8 bf = *(const short8*)&sXT[wh * 32 + nt * 16 + lr][kof];
        acc_y[nt] = mfma16(af, bf, acc_y[nt]);
      }
    }
#pragma unroll
    for (int nt = 0; nt < 2; ++nt)
#pragma unroll
      for (int rr = 0; rr < 4; ++rr) {
        int l = lq * 16 + lg * 4 + rr;
        int p = wh * 32 + nt * 16 + lr;
        int tg = c * 64 + l;
        if (tg <= LSEQ - 2) {
          float v = acc_y[nt][rr];
          if (dir == 0)
            y0[((size_t)bt * LSEQ + tg + 1) * DINNER + h * 64 + p] = f2bf(v);
          else
            y1[((size_t)bt * LSEQ + (LSEQ - 2 - tg)) * DINNER + h * 64 + p] = f2bf(v);
        }
      }
    if (c == 0 && tid < 64) {
      if (dir == 0)
        y0[((size_t)bt * LSEQ) * DINNER + h * 64 + tid] = 0;
      else
        y1[((size_t)bt * LSEQ + (LSEQ - 1)) * DINNER + h * 64 + tid] = 0;
    }
    // chunk state: S = lam*S + (X*w)^T @ B
    {
      f32x4 acc_s[2] = {};
#pragma unroll
      for (int ks = 0; ks < 2; ++ks) {
        int kof = ks * 32 + lg * 8;
        ushort8 xr = *(const ushort8*)&sXT[lq * 16 + lr][kof];
        short8 af;
#pragma unroll
        for (int e = 0; e < 8; ++e) af[e] = (short)f2bf(bf2f(xr[e]) * sSc[kof + e]);
#pragma unroll
        for (int nt = 0; nt < 2; ++nt) {
          short8 bf = *(const short8*)&sBT[wh * 32 + nt * 16 + lr][kof];
          acc_s[nt] = mfma16(af, bf, acc_s[nt]);
        }
      }
      float lam = sEA[63];
#pragma unroll
      for (int nt = 0; nt < 2; ++nt)
#pragma unroll
        for (int rr = 0; rr < 4; ++rr) {
          int p = lq * 16 + lg * 4 + rr;
          int n = wh * 32 + nt * 16 + lr;
          float ns = lam * sS[p][n] + acc_s[nt][rr];
          sS[p][n] = ns;
          sSb[p][n] = f2bf(ns);
        }
    }
    __syncthreads();  // bar4
  }
}

// ---------------- Deff = x @ fc_D_w^T + D  (MFMA, split-K, 32 rows/block) ----------------
__global__ __launch_bounds__(256) void k_deff(const u16* __restrict__ xcv,
                                              const u16* __restrict__ fwb,
                                              const float* __restrict__ Dv,
                                              float* __restrict__ deff) {
  __shared__ float red[2][64][8];
  const int tid = threadIdx.x, wave = tid >> 6, lane = tid & 63;
  const int lr = lane & 15, lg = lane >> 4;
  const int rowg = wave & 1;
  const int kg = wave >> 1;
  const int rb = blockIdx.x * 32 + rowg * 16;
  const u16* xrow = xcv + (size_t)(rb + lr) * DINNER + kg * 1024 + lg * 8;
  const u16* f0 = fwb + (size_t)lr * DINNER + kg * 1024 + lg * 8;
  const u16* f1 = fwb + (size_t)(16 + lr) * DINNER + kg * 1024 + lg * 8;
  f32x4 a0 = {}, a1 = {};
  for (int k = 0; k < 1024; k += 32) {
    short8 bf = *(const short8*)(xrow + k);
    short8 af0 = *(const short8*)(f0 + k);
    short8 af1 = *(const short8*)(f1 + k);
    a0 = mfma16(af0, bf, a0);
    a1 = mfma16(af1, bf, a1);
  }
  if (kg == 1) {
#pragma unroll
    for (int rr = 0; rr < 4; ++rr) {
      red[rowg][lane][rr] = a0[rr];
      red[rowg][lane][4 + rr] = a1[rr];
    }
  }
  __syncthreads();
  if (kg == 0) {
    float4 o0, o1;
#pragma unroll
    for (int rr = 0; rr < 4; ++rr) {
      ((float*)&o0)[rr] = a0[rr] + red[rowg][lane][rr] + Dv[lg * 4 + rr];
      ((float*)&o1)[rr] = a1[rr] + red[rowg][lane][4 + rr] + Dv[16 + lg * 4 + rr];
    }
    *(float4*)&deff[(size_t)(rb + lr) * NH + lg * 4] = o0;
    *(float4*)&deff[(size_t)(rb + lr) * NH + 16 + lg * 4] = o1;
  }
}

// ---------------- gating: yn = rmsnorm((y0 + y1 + x*Deff) * silu(z)) * gnw ----------------
__global__ __launch_bounds__(256) void k_gate(const u16* __restrict__ yb0,
                                              const u16* __restrict__ yb1,
                                              const u16* __restrict__ xcv,
                                              const float* __restrict__ deff,
                                              const u16* __restrict__ zb,
                                              const float* __restrict__ gnw,
                                              u16* __restrict__ yn) {
  int row = blockIdx.x, t = threadIdx.x;
  size_t base = (size_t)row * DINNER + t * 8;
  ushort8 y0v = *(const ushort8*)(yb0 + base);
  ushort8 y1v = *(const ushort8*)(yb1 + base);
  ushort8 xv = *(const ushort8*)(xcv + base);
  ushort8 zv = *(const ushort8*)(zb + base);
  float de = deff[row * NH + (t >> 3)];
  float g[8];
  float ss = 0.f;
#pragma unroll
  for (int j = 0; j < 8; ++j) {
    float y = bf2f(y0v[j]) + bf2f(y1v[j]) + bf2f(xv[j]) * de;
    float z = bf2f(zv[j]);
    float gg = y * (z / (1.f + expf(-z)));
    g[j] = gg;
    ss += gg * gg;
  }
  for (int m = 32; m; m >>= 1) ss += __shfl_xor(ss, m);
  __shared__ float wsum[4];
  if ((t & 63) == 0) wsum[t >> 6] = ss;
  __syncthreads();
  float tot = wsum[0] + wsum[1] + wsum[2] + wsum[3];
  float rinv = rsqrtf(tot * (1.0f / DINNER) + 1e-5f);
  u32 w0 = (u32)f2bf(g[0] * rinv * gnw[t * 8 + 0]) | ((u32)f2bf(g[1] * rinv * gnw[t * 8 + 1]) << 16);
  u32 w1 = (u32)f2bf(g[2] * rinv * gnw[t * 8 + 2]) | ((u32)f2bf(g[3] * rinv * gnw[t * 8 + 3]) << 16);
  u32 w2 = (u32)f2bf(g[4] * rinv * gnw[t * 8 + 4]) | ((u32)f2bf(g[5] * rinv * gnw[t * 8 + 5]) << 16);
  u32 w3 = (u32)f2bf(g[6] * rinv * gnw[t * 8 + 6]) | ((u32)f2bf(g[7] * rinv * gnw[t * 8 + 7]) << 16);
  *(uint4*)(yn + base) = make_uint4(w0, w1, w2, w3);
}

extern "C" void kernel_launch(void* const* d_in, const int* in_sizes, int n_in,
                              void* d_out, int out_size, void* d_ws, size_t ws_size,
                              hipStream_t stream) {
  (void)in_sizes; (void)n_in; (void)out_size; (void)ws_size;
  const float* hid = (const float*)d_in[0];
  const float* resin = (const float*)d_in[1];
  const float* nw = (const float*)d_in[2];
  const float* w1 = (const float*)d_in[3];
  const float* cw = (const float*)d_in[4];
  const float* cb = (const float*)d_in[5];
  const float* dtb = (const float*)d_in[6];
  const float* alog = (const float*)d_in[7];
  const float* Dv = (const float*)d_in[8];
  const float* fcw = (const float*)d_in[9];
  const float* gnw = (const float*)d_in[10];
  const float* w2 = (const float*)d_in[11];
  float* out = (float*)d_out;
  float* resout = out + (size_t)ROWS * DMODEL;

  char* ws = (char*)d_ws;
  size_t o = 0;
  auto alloc = [&](size_t bytes) {
    char* p = ws + o;
    o += (bytes + 255) & ~(size_t)255;
    return p;
  };
  u16* W1b = (u16*)alloc((size_t)DIP_PAD * DMODEL * 2);  // 8.9 MB (reused for W2b)
  u16* HN = (u16*)alloc((size_t)ROWS * DMODEL * 2);      // 16.8 MB (reused for YN)
  u16* XBC = (u16*)alloc((size_t)ROWS * CONVD * 2);      // 35.7 MB (reused for YB0)
  u16* ZB = (u16*)alloc((size_t)ROWS * DINNER * 2);      // 33.6 MB
  u16* XC = (u16*)alloc((size_t)ROWS * DINNER * 2);      // 33.6 MB
  u16* BM = (u16*)alloc((size_t)ROWS * 64 * 2);          // 1 MB
  u16* CM = (u16*)alloc((size_t)ROWS * 64 * 2);          // 1 MB
  float* DT = (float*)alloc((size_t)8 * LSEQ * NH * 4);  // 2 MB
  float* DE = (float*)alloc((size_t)ROWS * NH * 4);      // 1 MB
  u16* FWB = (u16*)alloc((size_t)NH * DINNER * 2);       // 128 KB
  u16* YB0 = XBC;
  u16* YB1 = (u16*)out;  // out region (33.55 MB) is dead until final GEMM
  u16* W2b = W1b;
  u16* YN = HN;

  k_cast<<<(DIP * DMODEL) / 1024, 256, 0, stream>>>(w1, W1b);
  k_addnorm<<<ROWS, 256, 0, stream>>>(hid, resin, nw, resout, HN);
  // in_proj: M=8192 (64 tiles of 128), N=4352 (17 tiles of 256), K=1024
  k_gemm<0><<<64 * 17, 512, 0, stream>>>(HN, W1b, DMODEL, 17, nullptr, ZB, XBC, DT, dtb);
  k_conv<<<(ROWS * 272) / 256, 256, 0, stream>>>(XBC, cw, cb, XC, BM, CM);
  k_ssd<<<256, 512, 0, stream>>>(XC, BM, CM, DT, alog, YB0, YB1);
  k_cast<<<(DMODEL * DINNER) / 1024, 256, 0, stream>>>(w2, W2b);
  k_cast<<<(NH * DINNER) / 1024, 256, 0, stream>>>(fcw, FWB);
  k_deff<<<ROWS / 32, 256, 0, stream>>>(XC, FWB, Dv, DE);
  k_gate<<<ROWS, 256, 0, stream>>>(YB0, YB1, XC, DE, ZB, gnw, YN);
  // out_proj: M=8192 (64 tiles), N=1024 (4 tiles of 256), K=2048
  k_gemm<1><<<64 * 4, 512, 0, stream>>>(YN, W2b, DINNER, 4, out, nullptr, nullptr, nullptr,
                                        nullptr);
}